// Round 2
// 339.125 us; speedup vs baseline: 1.2106x; 1.2106x over previous
//
#include <hip/hip_runtime.h>
#include <hip/hip_bf16.h>

// Problem constants (from setup_inputs)
#define N_EMB   6272
#define M_BANK  32768
#define D_DIM   128
#define KPACK   384      // hi|hi|lo vs hi|lo|hi packed K
#define BATCH   8
#define P_PATCH 784      // 6272 / 8
#define GRID_WH 28
#define OUT_WH  224
#define KNN     9
#define KSIZE   33
#define KRAD    16

typedef unsigned long long ull;
typedef short bf16x8 __attribute__((ext_vector_type(8)));
typedef float f32x4  __attribute__((ext_vector_type(4)));

// ---------------- workspace layout (bytes), ws ~256 MB ----------------
#define WS_MINPACK 0          // u64[6272]            -> 50176
#define WS_X2      50176      // f32[6272]            -> 75264
#define WS_Y2      75264      // f32[32768]           -> 206336
#define WS_PSCORE  206336     // f32[6272]            -> 231424
#define WS_BSCORE  231424     // f32[8]
#define WS_BMAXP   231456     // i32[8]
#define WS_BNN     231488     // i32[8]
#define WS_DNN     231552     // f32[8*32768]         -> 1280128
#define WS_APK     2885888    // u16[6272*384]        -> 7702784   (16B aligned)
#define WS_BPK     7702784    // u16[32768*384]       -> 32868608  (16B aligned)
#define WS_CAND    32868608   // u64[8*32*9]          -> 32887040

__device__ __forceinline__ ull umin64(ull a, ull b) { return a < b ? a : b; }
__device__ __forceinline__ ull umax64(ull a, ull b) { return a > b ? a : b; }

__device__ __forceinline__ void gload_lds16(const void* g, void* l) {
    __builtin_amdgcn_global_load_lds(
        (const __attribute__((address_space(1))) void*)g,
        (__attribute__((address_space(3))) void*)l, 16, 0, 0);
}

// ---------------------------------------------------------------------------
// Kernel 0 (prep): per-row bf16 hi/lo split-pack + sum-of-squares + minpack init.
// One wave per row. A rows: [hi|hi|lo]; B rows: [hi|lo|hi].
// ---------------------------------------------------------------------------
__global__ __launch_bounds__(256) void prep_kernel(
    const float* __restrict__ emb, const float* __restrict__ bank,
    unsigned short* __restrict__ Apk, unsigned short* __restrict__ Bpk,
    float* __restrict__ x2, float* __restrict__ y2, ull* __restrict__ minpack)
{
    const int tid = threadIdx.x;
    int gi = blockIdx.x * 256 + tid;
    if (gi < N_EMB) minpack[gi] = ~0ull;

    const int w    = blockIdx.x * 4 + (tid >> 6);
    const int lane = tid & 63;
    const float* src;
    unsigned short* dst;
    float* sq;
    int loOff, hi2Off;
    if (w < N_EMB) {
        src = emb + (size_t)w * D_DIM;
        dst = Apk + (size_t)w * KPACK;
        sq  = x2 + w;
        hi2Off = 128; loOff = 256;     // A: hi, hi, lo
    } else {
        int m = w - N_EMB;             // grid sized exactly -> m < M_BANK
        src = bank + (size_t)m * D_DIM;
        dst = Bpk + (size_t)m * KPACK;
        sq  = y2 + m;
        loOff = 128; hi2Off = 256;     // B: hi, lo, hi
    }
    float2 v = *(const float2*)&src[2 * lane];
    __hip_bfloat16 h0 = __float2bfloat16(v.x);
    __hip_bfloat16 h1 = __float2bfloat16(v.y);
    __hip_bfloat16 l0 = __float2bfloat16(v.x - __bfloat162float(h0));
    __hip_bfloat16 l1 = __float2bfloat16(v.y - __bfloat162float(h1));
    unsigned hb0 = *(unsigned short*)&h0, hb1 = *(unsigned short*)&h1;
    unsigned lb0 = *(unsigned short*)&l0, lb1 = *(unsigned short*)&l1;
    unsigned hpack = hb0 | (hb1 << 16);
    unsigned lpack = lb0 | (lb1 << 16);
    *(unsigned*)&dst[2 * lane]          = hpack;
    *(unsigned*)&dst[hi2Off + 2 * lane] = hpack;
    *(unsigned*)&dst[loOff + 2 * lane]  = lpack;

    float s = fmaf(v.x, v.x, v.y * v.y);
    #pragma unroll
    for (int off = 32; off > 0; off >>= 1) s += __shfl_down(s, off, 64);
    if (lane == 0) *sq = s;
}

// ---------------------------------------------------------------------------
// Kernel 1: MFMA distance + fused min/argmin.
// 128x128 tile, 16x16x32 bf16 MFMA, K=384 (hi/lo split).
// DOUBLE-BUFFERED global_load_lds pipeline with raw s_barrier + vmcnt(4).
//
//  (a) XOR bank-swizzle on the 16B K-segments (rule #21: linear LDS dest for
//      global_load_lds, inverse-swizzled GLOBAL source, same-XOR on ds_read).
//      key = (row>>1)&3; read side reduces to qa ^ ((ra>>1)&3) since wr*64 and
//      i*16 are 0 mod 4 after >>1. Makes each 8-lane issue phase hit all 8
//      16B bank-groups exactly once -> conflict-free ds_read_b128 (8 cyc).
//  (b) Epilogue: 64-bit shuffle-reduce (128 ds_swizzle/wave) replaced by an
//      LDS transpose-reduce into red2[128][32] (reuses tile LDS after a
//      barrier). min over unique packed u64 is order-independent -> selection
//      semantics bit-identical to before.
// ---------------------------------------------------------------------------
__global__ __launch_bounds__(256) void mfma_min_kernel(
    const unsigned short* __restrict__ Apk, const unsigned short* __restrict__ Bpk,
    const float* __restrict__ x2, const float* __restrict__ y2,
    ull* __restrict__ minpack)
{
    // 32 KB flat: A[2 bufs][128*32] then B[2 bufs][128*32]; epilogue reuses
    // the whole thing as red2[128][32] (ull).
    __shared__ __align__(16) unsigned short smem[4 * 128 * 32];
    unsigned short* Asm0 = smem;                 // [2][128*32]
    unsigned short* Bsm0 = smem + 2 * 128 * 32;  // [2][128*32]

    const int tid  = threadIdx.x;
    const int lane = tid & 63;
    const int wave = tid >> 6;
    const int wr = wave >> 1, wc = wave & 1;
    const int n0 = blockIdx.y * 128;
    const int m0 = blockIdx.x * 128;

    const int srow = tid >> 2;   // 0..63 staging row
    const int sseg = tid & 3;    // 16B segment within 64B row-chunk (LDS phys)
    const int ssw  = sseg ^ ((srow >> 1) & 3);   // swizzled GLOBAL segment

    const int qa = lane >> 4;    // k-quad (logical)
    const int ra = lane & 15;    // row-in-frag / col-in-C
    const int qsw = qa ^ ((ra >> 1) & 3);        // swizzled LDS segment to read

    f32x4 acc[4][4];
    #pragma unroll
    for (int i = 0; i < 4; ++i)
        #pragma unroll
        for (int j = 0; j < 4; ++j)
            acc[i][j] = (f32x4){0.f, 0.f, 0.f, 0.f};

    // global source: row base + swizzled segment (key identical for row and
    // row+64 since (+64)>>1 = +32 == 0 mod 4)
    const unsigned short* gA = Apk + (size_t)(n0 + srow) * KPACK + ssw * 8;
    const unsigned short* gB = Bpk + (size_t)(m0 + srow) * KPACK + ssw * 8;
    const int lofA = srow * 32 + sseg * 8;            // linear LDS dest (= tid*16B)
    const int lofB = (srow + 64) * 32 + sseg * 8;
    const int BUFE = 128 * 32;                        // elems per buffer

    // prologue: chunk 0 -> buffer 0
    gload_lds16(gA,              &Asm0[lofA]);
    gload_lds16(gA + 64 * KPACK, &Asm0[lofB]);
    gload_lds16(gB,              &Bsm0[lofA]);
    gload_lds16(gB + 64 * KPACK, &Bsm0[lofB]);

    for (int k = 0; k < 12; ++k) {
        const int cur = k & 1;
        const int nxt = cur ^ 1;
        // barrier#1: everyone is done reading buf[nxt] (cur of iter k-1)
        asm volatile("s_barrier" ::: "memory");
        if (k < 11) {
            const int ko = (k + 1) * 32;
            gload_lds16(gA + ko,              &Asm0[nxt * BUFE + lofA]);
            gload_lds16(gA + ko + 64 * KPACK, &Asm0[nxt * BUFE + lofB]);
            gload_lds16(gB + ko,              &Bsm0[nxt * BUFE + lofA]);
            gload_lds16(gB + ko + 64 * KPACK, &Bsm0[nxt * BUFE + lofB]);
            // 4 newest (prefetch) may remain in flight; cur's 4 are older
            asm volatile("s_waitcnt vmcnt(4)" ::: "memory");
        } else {
            asm volatile("s_waitcnt vmcnt(0)" ::: "memory");
        }
        // barrier#2: buf[cur] complete in every wave
        asm volatile("s_barrier" ::: "memory");

        const unsigned short* As = &Asm0[cur * BUFE];
        const unsigned short* Bs = &Bsm0[cur * BUFE];
        bf16x8 af[4], bfr[4];
        #pragma unroll
        for (int i = 0; i < 4; ++i)
            af[i] = *(const bf16x8*)&As[(wr * 64 + i * 16 + ra) * 32 + qsw * 8];
        #pragma unroll
        for (int j = 0; j < 4; ++j)
            bfr[j] = *(const bf16x8*)&Bs[(wc * 64 + j * 16 + ra) * 32 + qsw * 8];
        #pragma unroll
        for (int i = 0; i < 4; ++i)
            #pragma unroll
            for (int j = 0; j < 4; ++j)
                acc[i][j] = __builtin_amdgcn_mfma_f32_16x16x32_bf16(af[i], bfr[j], acc[i][j], 0, 0, 0);
    }

    // ---- epilogue: d2 = x2 + y2 - 2*dot, clamp, pack, LDS transpose-reduce ----
    float y2v[4];
    #pragma unroll
    for (int j = 0; j < 4; ++j) y2v[j] = y2[m0 + wc * 64 + j * 16 + ra];

    ull (*red2)[32] = (ull (*)[32])smem;   // 128 rows x 32 (wc*16+ra) = 32 KB

    // all waves must be done reading the K-tiles before red2 overwrites them
    __syncthreads();

    #pragma unroll
    for (int i = 0; i < 4; ++i) {
        #pragma unroll
        for (int r = 0; r < 4; ++r) {
            const int rowl = wr * 64 + i * 16 + qa * 4 + r;
            const float xv = x2[n0 + rowl];
            ull mn = ~0ull;
            #pragma unroll
            for (int j = 0; j < 4; ++j) {
                const int m = m0 + wc * 64 + j * 16 + ra;
                float d2 = fmaf(-2.0f, acc[i][j][r], xv + y2v[j]);
                d2 = fmaxf(d2, 0.0f);
                ull p = ((ull)__float_as_uint(d2) << 32) | (unsigned)m;
                mn = umin64(mn, p);
            }
            // write pattern: distinct (row,col) per thread-iter; 4 clean phases
            red2[rowl][wc * 16 + ra] = mn;
        }
    }
    __syncthreads();
    if (tid < 128) {
        const int l = tid & 63;
        ull mn = ~0ull;
        #pragma unroll
        for (int k = 0; k < 32; ++k)     // lane-staggered cols: distinct bank pairs
            mn = umin64(mn, red2[tid][(k + l) & 31]);
        atomicMin(&minpack[n0 + tid], mn);
    }
}

// ---------------------------------------------------------------------------
// Kernel 2: per-batch argmax of patch scores (fused unpack; argmax over d2
// == argmax over sqrt(d2)); writes pscore for the blur path.
// ---------------------------------------------------------------------------
__global__ __launch_bounds__(256) void batch_argmax_kernel(
    const ull* __restrict__ minpack, float* __restrict__ pscore,
    float* __restrict__ bscore, int* __restrict__ bmaxp, int* __restrict__ bnn)
{
    __shared__ ull red[256];
    int b = blockIdx.x, tid = threadIdx.x;
    ull local = 0;
    for (int p = tid; p < P_PATCH; p += 256) {
        ull mp = minpack[b * P_PATCH + p];
        unsigned d2b = (unsigned)(mp >> 32);
        pscore[b * P_PATCH + p] = sqrtf(__uint_as_float(d2b));
        ull pk = ((ull)d2b << 32) | (unsigned)(p ^ 0xFFFFFFFFu);
        local = umax64(local, pk);
    }
    red[tid] = local;
    __syncthreads();
    for (int s = 128; s > 0; s >>= 1) {
        if (tid < s) red[tid] = umax64(red[tid], red[tid + s]);
        __syncthreads();
    }
    if (tid == 0) {
        ull r = red[0];
        int p = (int)(((unsigned)(r & 0xFFFFFFFFu)) ^ 0xFFFFFFFFu);
        bscore[b] = sqrtf(__uint_as_float((unsigned)(r >> 32)));
        bmaxp[b]  = p;
        bnn[b]    = (int)(minpack[b * P_PATCH + p] & 0xFFFFFFFFu);
    }
}

// ---------------------------------------------------------------------------
// Kernel 3: d_nn = dist(nn_sample[b], memory_bank) -> (8, M)
// ---------------------------------------------------------------------------
__global__ __launch_bounds__(256) void dnn_kernel(
    const float* __restrict__ bank, const float* __restrict__ y2,
    const int* __restrict__ bnn, float* __restrict__ dnn)
{
    __shared__ float nn[BATCH][D_DIM];
    __shared__ float nny2[BATCH];
    int tid = threadIdx.x;
    for (int i = tid; i < BATCH * D_DIM; i += 256) {
        int b = i >> 7, d = i & 127;
        nn[b][d] = bank[(size_t)bnn[b] * D_DIM + d];
    }
    if (tid < BATCH) nny2[tid] = y2[bnn[tid]];
    __syncthreads();

    int w = tid >> 6, lane = tid & 63;
    int m = blockIdx.x * 4 + w;
    float2 v = *(const float2*)&bank[(size_t)m * D_DIM + 2 * lane];
    float part[BATCH];
    #pragma unroll
    for (int b = 0; b < BATCH; ++b)
        part[b] = fmaf(v.x, nn[b][2 * lane], v.y * nn[b][2 * lane + 1]);
    #pragma unroll
    for (int b = 0; b < BATCH; ++b) {
        float s = part[b];
        #pragma unroll
        for (int off = 32; off > 0; off >>= 1) s += __shfl_down(s, off, 64);
        if (lane == 0) {
            float d2 = nny2[b] + y2[m] - 2.0f * s;
            dnn[b * M_BANK + m] = sqrtf(fmaxf(d2, 0.0f));
        }
    }
}

// ---------------------------------------------------------------------------
// Kernel 4a: per-(batch, 1024-chunk) local top-9 of d_nn.
// ---------------------------------------------------------------------------
__global__ __launch_bounds__(256) void topk_part_kernel(
    const float* __restrict__ dnn, ull* __restrict__ cand)
{
    __shared__ ull vals[1024];
    __shared__ ull red[256];
    const int tid = threadIdx.x;
    const int b = blockIdx.y, ch = blockIdx.x;
    const int base = ch * 1024;

    #pragma unroll
    for (int j = 0; j < 4; ++j) {
        int i = base + tid + j * 256;
        vals[tid + j * 256] = ((ull)__float_as_uint(dnn[b * M_BANK + i]) << 32) | (unsigned)i;
    }
    __syncthreads();

    for (int k = 0; k < KNN; ++k) {
        ull local = vals[tid];
        #pragma unroll
        for (int j = 1; j < 4; ++j) local = umin64(local, vals[tid + j * 256]);
        red[tid] = local;
        __syncthreads();
        for (int s = 128; s > 0; s >>= 1) {
            if (tid < s) red[tid] = umin64(red[tid], red[tid + s]);
            __syncthreads();
        }
        ull win = red[0];
        if (tid == 0) cand[(b * 32 + ch) * KNN + k] = win;
        #pragma unroll
        for (int j = 0; j < 4; ++j)
            if (vals[tid + j * 256] == win) vals[tid + j * 256] = ~0ull;
        __syncthreads();
    }
}

// ---------------------------------------------------------------------------
// Kernel 4b: per-batch final top-9 from 288 candidates + rescore
// ---------------------------------------------------------------------------
__global__ __launch_bounds__(256) void topk_final_kernel(
    const ull* __restrict__ cand,
    const float* __restrict__ emb, const float* __restrict__ bank,
    const float* __restrict__ x2, const float* __restrict__ y2,
    const float* __restrict__ bscore, const int* __restrict__ bmaxp,
    float* __restrict__ out)
{
    __shared__ ull vals[512];
    __shared__ ull red[256];
    __shared__ int chosen[KNN];
    __shared__ float dists[KNN];
    const int tid = threadIdx.x;
    const int b = blockIdx.x;

    vals[tid]       = (tid < 32 * KNN) ? cand[b * 32 * KNN + tid] : ~0ull;
    vals[tid + 256] = (tid + 256 < 32 * KNN) ? cand[b * 32 * KNN + tid + 256] : ~0ull;
    __syncthreads();

    for (int k = 0; k < KNN; ++k) {
        red[tid] = umin64(vals[tid], vals[tid + 256]);
        __syncthreads();
        for (int s = 128; s > 0; s >>= 1) {
            if (tid < s) red[tid] = umin64(red[tid], red[tid + s]);
            __syncthreads();
        }
        ull win = red[0];
        if (tid == 0) chosen[k] = (int)(win & 0xFFFFFFFFu);
        if (vals[tid] == win) vals[tid] = ~0ull;
        if (vals[tid + 256] == win) vals[tid + 256] = ~0ull;
        __syncthreads();
    }

    const int e = b * P_PATCH + bmaxp[b];
    if (tid < KNN) {
        const float* mf = emb + (size_t)e * D_DIM;
        const float* ms = bank + (size_t)chosen[tid] * D_DIM;
        float dot = 0.0f;
        for (int d = 0; d < D_DIM; ++d) dot = fmaf(mf[d], ms[d], dot);
        float d2 = x2[e] - 2.0f * dot + y2[chosen[tid]];
        dists[tid] = sqrtf(fmaxf(d2, 0.0f));
    }
    __syncthreads();
    if (tid == 0) {
        float mx = dists[0];
        for (int k = 1; k < KNN; ++k) mx = fmaxf(mx, dists[k]);
        float s = 0.0f;
        for (int k = 0; k < KNN; ++k) s += expf(dists[k] - mx);
        float w = 1.0f - expf(dists[0] - mx) / s;
        out[b] = w * bscore[b];
    }
}

// ---------------------------------------------------------------------------
// Kernel 5: fully-fused resize + separable Gaussian blur (exact regroup).
// ---------------------------------------------------------------------------
__device__ __forceinline__ int refl224(int i) {
    if (i < 0) i = -i;
    if (i >= OUT_WH) i = 2 * (OUT_WH - 1) - i;
    return i;
}

__global__ __launch_bounds__(256) void blur_fused_kernel(
    const float* __restrict__ pscore, float* __restrict__ outp)
{
    __shared__ float g[KSIZE];
    __shared__ float ps[P_PATCH];
    __shared__ float q[GRID_WH * OUT_WH];
    __shared__ float hq[GRID_WH * OUT_WH];
    __shared__ float wrow[32][GRID_WH];

    const int tid = threadIdx.x;
    const int band = blockIdx.x;      // 0..6
    const int b    = blockIdx.y;      // 0..7

    if (tid < KSIZE) {
        float x = (tid - KRAD) * 0.25f;
        g[tid] = __expf(-0.5f * x * x);
    }
    for (int i = tid; i < P_PATCH; i += 256) ps[i] = pscore[b * P_PATCH + i];
    __syncthreads();
    if (tid == 0) {
        float s = 0.0f;
        for (int i = 0; i < KSIZE; ++i) s += g[i];
        float inv = 1.0f / s;
        for (int i = 0; i < KSIZE; ++i) g[i] *= inv;
    }
    __syncthreads();

    for (int i = tid; i < GRID_WH * OUT_WH; i += 256) {
        int gy = i / OUT_WH, x = i - gy * OUT_WH;
        float cx = (2 * x - 7) * 0.0625f;
        int ix = (int)floorf(cx); float fx = cx - ix;
        int x0 = min(max(ix, 0), GRID_WH - 1), x1 = min(max(ix + 1, 0), GRID_WH - 1);
        q[i] = ps[gy * GRID_WH + x0] * (1.0f - fx) + ps[gy * GRID_WH + x1] * fx;
    }

    if (tid < 32) {
        int y = band * 32 + tid;
        for (int gy = 0; gy < GRID_WH; ++gy) wrow[tid][gy] = 0.0f;
        for (int t = 0; t < KSIZE; ++t) {
            int yy = refl224(y - KRAD + t);
            float cy = (2 * yy - 7) * 0.0625f;
            int iy = (int)floorf(cy); float fy = cy - iy;
            int y0 = min(max(iy, 0), GRID_WH - 1), y1 = min(max(iy + 1, 0), GRID_WH - 1);
            wrow[tid][y0] += g[t] * (1.0f - fy);
            wrow[tid][y1] += g[t] * fy;
        }
    }
    __syncthreads();

    for (int i = tid; i < GRID_WH * OUT_WH; i += 256) {
        int gy = i / OUT_WH, x = i - gy * OUT_WH;
        float s = 0.0f;
        #pragma unroll
        for (int t = 0; t < KSIZE; ++t)
            s = fmaf(g[t], q[gy * OUT_WH + refl224(x - KRAD + t)], s);
        hq[i] = s;
    }
    __syncthreads();

    const int yl = tid >> 3;                 // 0..31
    const int xbase = (tid & 7) * 28;        // 8 groups x 28 px = 224
    const int y = band * 32 + yl;
    float* orow = outp + ((size_t)b * OUT_WH + y) * OUT_WH;
    for (int i = 0; i < 28; ++i) {
        int x = xbase + i;
        float s = 0.0f;
        #pragma unroll
        for (int gy = 0; gy < GRID_WH; ++gy)
            s = fmaf(wrow[yl][gy], hq[gy * OUT_WH + x], s);
        orow[x] = s;
    }
}

// ---------------------------------------------------------------------------
extern "C" void kernel_launch(void* const* d_in, const int* in_sizes, int n_in,
                              void* d_out, int out_size, void* d_ws, size_t ws_size,
                              hipStream_t stream) {
    const float* emb  = (const float*)d_in[0];
    const float* bank = (const float*)d_in[1];
    float* out = (float*)d_out;

    char* ws = (char*)d_ws;
    ull*   minpack = (ull*)(ws + WS_MINPACK);
    float* x2      = (float*)(ws + WS_X2);
    float* y2      = (float*)(ws + WS_Y2);
    float* pscore  = (float*)(ws + WS_PSCORE);
    float* bscore  = (float*)(ws + WS_BSCORE);
    int*   bmaxp   = (int*)(ws + WS_BMAXP);
    int*   bnn     = (int*)(ws + WS_BNN);
    float* dnn     = (float*)(ws + WS_DNN);
    unsigned short* Apk = (unsigned short*)(ws + WS_APK);
    unsigned short* Bpk = (unsigned short*)(ws + WS_BPK);
    ull*   cand    = (ull*)(ws + WS_CAND);

    // 0: split-pack + sumsq + minpack init (one wave per row)
    prep_kernel<<<(N_EMB + M_BANK) / 4, 256, 0, stream>>>(emb, bank, Apk, Bpk, x2, y2, minpack);
    // 1: MFMA distance + fused min/argmin (2-D grid)
    {
        dim3 grid(M_BANK / 128, N_EMB / 128);   // 256 x 49
        mfma_min_kernel<<<grid, 256, 0, stream>>>(Apk, Bpk, x2, y2, minpack);
    }
    // 2: per-batch argmax (+ pscore unpack)
    batch_argmax_kernel<<<BATCH, 256, 0, stream>>>(minpack, pscore, bscore, bmaxp, bnn);
    // 3: d_nn
    dnn_kernel<<<M_BANK / 4, 256, 0, stream>>>(bank, y2, bnn, dnn);
    // 4a: per-chunk top-9 candidates
    {
        dim3 grid(32, BATCH);
        topk_part_kernel<<<grid, 256, 0, stream>>>(dnn, cand);
    }
    // 4b: final top-9 + rescore -> out[0..7]
    topk_final_kernel<<<BATCH, 256, 0, stream>>>(cand, emb, bank, x2, y2, bscore, bmaxp, out);
    // 5: fused resize + full separable blur -> out[8..]
    {
        dim3 grid(OUT_WH / 32, BATCH);
        blur_fused_kernel<<<grid, 256, 0, stream>>>(pscore, out + BATCH);
    }
}

// Round 3
// 322.816 us; speedup vs baseline: 1.2718x; 1.0505x over previous
//
#include <hip/hip_runtime.h>
#include <hip/hip_bf16.h>

// Problem constants (from setup_inputs)
#define N_EMB   6272
#define M_BANK  32768
#define D_DIM   128
#define KPACK   384      // hi|hi|lo vs hi|lo|hi packed K
#define BATCH   8
#define P_PATCH 784      // 6272 / 8
#define GRID_WH 28
#define OUT_WH  224
#define KNN     9
#define KSIZE   33
#define KRAD    16

typedef unsigned long long ull;
typedef short bf16x8 __attribute__((ext_vector_type(8)));
typedef float f32x4  __attribute__((ext_vector_type(4)));

// ---------------- workspace layout (bytes), ws ~256 MB ----------------
#define WS_MINPACK 0          // u64[6272]            -> 50176
#define WS_X2      50176      // f32[6272]            -> 75264
#define WS_Y2      75264      // f32[32768]           -> 206336
#define WS_PSCORE  206336     // f32[6272]            -> 231424
#define WS_BSCORE  231424     // f32[8]
#define WS_BMAXP   231456     // i32[8]
#define WS_BNN     231488     // i32[8]
#define WS_DNN     231552     // f32[8*32768]         -> 1280128
#define WS_APK     2885888    // u16[6272*384]        -> 7702784   (16B aligned)
#define WS_BPK     7702784    // u16[32768*384]       -> 32868608  (16B aligned)
#define WS_CAND    32868608   // u64[8*32*9]          -> 32887040

__device__ __forceinline__ ull umin64(ull a, ull b) { return a < b ? a : b; }
__device__ __forceinline__ ull umax64(ull a, ull b) { return a > b ? a : b; }

__device__ __forceinline__ void gload_lds16(const void* g, void* l) {
    __builtin_amdgcn_global_load_lds(
        (const __attribute__((address_space(1))) void*)g,
        (__attribute__((address_space(3))) void*)l, 16, 0, 0);
}

// ---------------------------------------------------------------------------
// Kernel 0 (prep): per-row bf16 hi/lo split-pack + sum-of-squares + minpack init.
// One wave per row. A rows: [hi|hi|lo]; B rows: [hi|lo|hi].
// ---------------------------------------------------------------------------
__global__ __launch_bounds__(256) void prep_kernel(
    const float* __restrict__ emb, const float* __restrict__ bank,
    unsigned short* __restrict__ Apk, unsigned short* __restrict__ Bpk,
    float* __restrict__ x2, float* __restrict__ y2, ull* __restrict__ minpack)
{
    const int tid = threadIdx.x;
    int gi = blockIdx.x * 256 + tid;
    if (gi < N_EMB) minpack[gi] = ~0ull;

    const int w    = blockIdx.x * 4 + (tid >> 6);
    const int lane = tid & 63;
    const float* src;
    unsigned short* dst;
    float* sq;
    int loOff, hi2Off;
    if (w < N_EMB) {
        src = emb + (size_t)w * D_DIM;
        dst = Apk + (size_t)w * KPACK;
        sq  = x2 + w;
        hi2Off = 128; loOff = 256;     // A: hi, hi, lo
    } else {
        int m = w - N_EMB;             // grid sized exactly -> m < M_BANK
        src = bank + (size_t)m * D_DIM;
        dst = Bpk + (size_t)m * KPACK;
        sq  = y2 + m;
        loOff = 128; hi2Off = 256;     // B: hi, lo, hi
    }
    float2 v = *(const float2*)&src[2 * lane];
    __hip_bfloat16 h0 = __float2bfloat16(v.x);
    __hip_bfloat16 h1 = __float2bfloat16(v.y);
    __hip_bfloat16 l0 = __float2bfloat16(v.x - __bfloat162float(h0));
    __hip_bfloat16 l1 = __float2bfloat16(v.y - __bfloat162float(h1));
    unsigned hb0 = *(unsigned short*)&h0, hb1 = *(unsigned short*)&h1;
    unsigned lb0 = *(unsigned short*)&l0, lb1 = *(unsigned short*)&l1;
    unsigned hpack = hb0 | (hb1 << 16);
    unsigned lpack = lb0 | (lb1 << 16);
    *(unsigned*)&dst[2 * lane]          = hpack;
    *(unsigned*)&dst[hi2Off + 2 * lane] = hpack;
    *(unsigned*)&dst[loOff + 2 * lane]  = lpack;

    float s = fmaf(v.x, v.x, v.y * v.y);
    #pragma unroll
    for (int off = 32; off > 0; off >>= 1) s += __shfl_down(s, off, 64);
    if (lane == 0) *sq = s;
}

// ---------------------------------------------------------------------------
// Kernel 1: MFMA distance + fused min/argmin.
// NEW: 128x256 block tile (A emb rows 128, B bank rows 256), 4 waves, each
// wave owns a 64x128 output tile -> LDS ds_read volume per output drops 25%
// (12 b128 per 64x128 per chunk vs 8 per 64x64), staging rows per block-output
// drop 25% (384 rows per 2x-area block). Same swizzle (key=(ra>>1)&3), same
// MFMA sequence per output -> bit-identical numerics.
// 48 KB LDS: A[2][128*32] + B[2][256*32]; epilogue red2[128][32] overlays.
// ---------------------------------------------------------------------------
__global__ __launch_bounds__(256) void mfma_min_kernel(
    const unsigned short* __restrict__ Apk, const unsigned short* __restrict__ Bpk,
    const float* __restrict__ x2, const float* __restrict__ y2,
    ull* __restrict__ minpack)
{
    __shared__ __align__(16) unsigned short smem[2 * 128 * 32 + 2 * 256 * 32]; // 48 KB
    unsigned short* AsmB = smem;                 // [2][128*32]
    unsigned short* BsmB = smem + 2 * 128 * 32;  // [2][256*32]
    const int ABUF = 128 * 32;
    const int BBUF = 256 * 32;

    const int tid  = threadIdx.x;
    const int lane = tid & 63;
    const int wave = tid >> 6;
    const int wr = wave >> 1, wc = wave & 1;     // wave tile: 64 (emb) x 128 (bank)
    const int n0 = blockIdx.y * 128;
    const int m0 = blockIdx.x * 256;

    const int srow = tid >> 2;   // 0..63 staging base row
    const int sseg = tid & 3;    // 16B segment (LDS phys)
    const int ssw  = sseg ^ ((srow >> 1) & 3);   // swizzled GLOBAL segment
                                                 // (key same for srow+64/128/192)

    const int qa = lane >> 4;    // k-quad (logical)
    const int ra = lane & 15;    // row-in-frag / col-in-C
    const int qsw = qa ^ ((ra >> 1) & 3);        // swizzled LDS segment to read

    f32x4 acc[4][8];
    #pragma unroll
    for (int i = 0; i < 4; ++i)
        #pragma unroll
        for (int j = 0; j < 8; ++j)
            acc[i][j] = (f32x4){0.f, 0.f, 0.f, 0.f};

    const unsigned short* gA = Apk + (size_t)(n0 + srow) * KPACK + ssw * 8;
    const unsigned short* gB = Bpk + (size_t)(m0 + srow) * KPACK + ssw * 8;
    const int lofA0 = srow * 32 + sseg * 8;           // linear LDS dests
    const int lofA1 = (srow + 64) * 32 + sseg * 8;
    const int lofB0 = lofA0;
    const int lofB1 = lofA1;
    const int lofB2 = (srow + 128) * 32 + sseg * 8;
    const int lofB3 = (srow + 192) * 32 + sseg * 8;

    // prologue: chunk 0 -> buffer 0 (6 loads)
    gload_lds16(gA,               &AsmB[lofA0]);
    gload_lds16(gA + 64 * KPACK,  &AsmB[lofA1]);
    gload_lds16(gB,               &BsmB[lofB0]);
    gload_lds16(gB + 64 * KPACK,  &BsmB[lofB1]);
    gload_lds16(gB + 128 * KPACK, &BsmB[lofB2]);
    gload_lds16(gB + 192 * KPACK, &BsmB[lofB3]);

    for (int k = 0; k < 12; ++k) {
        const int cur = k & 1;
        const int nxt = cur ^ 1;
        // barrier#1: everyone is done reading buf[nxt] (cur of iter k-1)
        asm volatile("s_barrier" ::: "memory");
        if (k < 11) {
            const int ko = (k + 1) * 32;
            gload_lds16(gA + ko,               &AsmB[nxt * ABUF + lofA0]);
            gload_lds16(gA + ko + 64 * KPACK,  &AsmB[nxt * ABUF + lofA1]);
            gload_lds16(gB + ko,               &BsmB[nxt * BBUF + lofB0]);
            gload_lds16(gB + ko + 64 * KPACK,  &BsmB[nxt * BBUF + lofB1]);
            gload_lds16(gB + ko + 128 * KPACK, &BsmB[nxt * BBUF + lofB2]);
            gload_lds16(gB + ko + 192 * KPACK, &BsmB[nxt * BBUF + lofB3]);
            // 6 newest (prefetch) may remain in flight; cur's 6 are older
            asm volatile("s_waitcnt vmcnt(6)" ::: "memory");
        } else {
            asm volatile("s_waitcnt vmcnt(0)" ::: "memory");
        }
        // barrier#2: buf[cur] complete in every wave
        asm volatile("s_barrier" ::: "memory");

        const unsigned short* As = &AsmB[cur * ABUF];
        const unsigned short* Bs = &BsmB[cur * BBUF];
        bf16x8 af[4];
        #pragma unroll
        for (int i = 0; i < 4; ++i)
            af[i] = *(const bf16x8*)&As[(wr * 64 + i * 16 + ra) * 32 + qsw * 8];
        #pragma unroll
        for (int j = 0; j < 8; ++j) {
            bf16x8 bj = *(const bf16x8*)&Bs[(wc * 128 + j * 16 + ra) * 32 + qsw * 8];
            #pragma unroll
            for (int i = 0; i < 4; ++i)
                acc[i][j] = __builtin_amdgcn_mfma_f32_16x16x32_bf16(af[i], bj, acc[i][j], 0, 0, 0);
        }
    }

    // ---- epilogue: d2 = x2 + y2 - 2*dot, clamp, pack, LDS transpose-reduce ----
    float y2v[8];
    #pragma unroll
    for (int j = 0; j < 8; ++j) y2v[j] = y2[m0 + wc * 128 + j * 16 + ra];

    ull (*red2)[32] = (ull (*)[32])smem;   // 128 rows x 32 (wc*16+ra) = 32 KB

    // all waves must be done reading the K-tiles before red2 overwrites them
    __syncthreads();

    #pragma unroll
    for (int i = 0; i < 4; ++i) {
        #pragma unroll
        for (int r = 0; r < 4; ++r) {
            const int rowl = wr * 64 + i * 16 + qa * 4 + r;
            const float xv = x2[n0 + rowl];
            ull mn = ~0ull;
            #pragma unroll
            for (int j = 0; j < 8; ++j) {
                const int m = m0 + wc * 128 + j * 16 + ra;
                float d2 = fmaf(-2.0f, acc[i][j][r], xv + y2v[j]);
                d2 = fmaxf(d2, 0.0f);
                ull p = ((ull)__float_as_uint(d2) << 32) | (unsigned)m;
                mn = umin64(mn, p);
            }
            red2[rowl][wc * 16 + ra] = mn;
        }
    }
    __syncthreads();
    if (tid < 128) {
        const int l = tid & 63;
        ull mn = ~0ull;
        #pragma unroll
        for (int k = 0; k < 32; ++k)     // lane-staggered cols: distinct bank pairs
            mn = umin64(mn, red2[tid][(k + l) & 31]);
        atomicMin(&minpack[n0 + tid], mn);
    }
}

// ---------------------------------------------------------------------------
// Kernel 2: per-batch argmax of patch scores (fused unpack; argmax over d2
// == argmax over sqrt(d2)); writes pscore for the blur path.
// ---------------------------------------------------------------------------
__global__ __launch_bounds__(256) void batch_argmax_kernel(
    const ull* __restrict__ minpack, float* __restrict__ pscore,
    float* __restrict__ bscore, int* __restrict__ bmaxp, int* __restrict__ bnn)
{
    __shared__ ull red[256];
    int b = blockIdx.x, tid = threadIdx.x;
    ull local = 0;
    for (int p = tid; p < P_PATCH; p += 256) {
        ull mp = minpack[b * P_PATCH + p];
        unsigned d2b = (unsigned)(mp >> 32);
        pscore[b * P_PATCH + p] = sqrtf(__uint_as_float(d2b));
        ull pk = ((ull)d2b << 32) | (unsigned)(p ^ 0xFFFFFFFFu);
        local = umax64(local, pk);
    }
    red[tid] = local;
    __syncthreads();
    for (int s = 128; s > 0; s >>= 1) {
        if (tid < s) red[tid] = umax64(red[tid], red[tid + s]);
        __syncthreads();
    }
    if (tid == 0) {
        ull r = red[0];
        int p = (int)(((unsigned)(r & 0xFFFFFFFFu)) ^ 0xFFFFFFFFu);
        bscore[b] = sqrtf(__uint_as_float((unsigned)(r >> 32)));
        bmaxp[b]  = p;
        bnn[b]    = (int)(minpack[b * P_PATCH + p] & 0xFFFFFFFFu);
    }
}

// ---------------------------------------------------------------------------
// Kernel 3: d_nn = dist(nn_sample[b], memory_bank) -> (8, M)
// ---------------------------------------------------------------------------
__global__ __launch_bounds__(256) void dnn_kernel(
    const float* __restrict__ bank, const float* __restrict__ y2,
    const int* __restrict__ bnn, float* __restrict__ dnn)
{
    __shared__ float nn[BATCH][D_DIM];
    __shared__ float nny2[BATCH];
    int tid = threadIdx.x;
    for (int i = tid; i < BATCH * D_DIM; i += 256) {
        int b = i >> 7, d = i & 127;
        nn[b][d] = bank[(size_t)bnn[b] * D_DIM + d];
    }
    if (tid < BATCH) nny2[tid] = y2[bnn[tid]];
    __syncthreads();

    int w = tid >> 6, lane = tid & 63;
    int m = blockIdx.x * 4 + w;
    float2 v = *(const float2*)&bank[(size_t)m * D_DIM + 2 * lane];
    float part[BATCH];
    #pragma unroll
    for (int b = 0; b < BATCH; ++b)
        part[b] = fmaf(v.x, nn[b][2 * lane], v.y * nn[b][2 * lane + 1]);
    #pragma unroll
    for (int b = 0; b < BATCH; ++b) {
        float s = part[b];
        #pragma unroll
        for (int off = 32; off > 0; off >>= 1) s += __shfl_down(s, off, 64);
        if (lane == 0) {
            float d2 = nny2[b] + y2[m] - 2.0f * s;
            dnn[b * M_BANK + m] = sqrtf(fmaxf(d2, 0.0f));
        }
    }
}

// ---------------------------------------------------------------------------
// Kernel 4a: per-(batch, 1024-chunk) local top-9 of d_nn.
// ---------------------------------------------------------------------------
__global__ __launch_bounds__(256) void topk_part_kernel(
    const float* __restrict__ dnn, ull* __restrict__ cand)
{
    __shared__ ull vals[1024];
    __shared__ ull red[256];
    const int tid = threadIdx.x;
    const int b = blockIdx.y, ch = blockIdx.x;
    const int base = ch * 1024;

    #pragma unroll
    for (int j = 0; j < 4; ++j) {
        int i = base + tid + j * 256;
        vals[tid + j * 256] = ((ull)__float_as_uint(dnn[b * M_BANK + i]) << 32) | (unsigned)i;
    }
    __syncthreads();

    for (int k = 0; k < KNN; ++k) {
        ull local = vals[tid];
        #pragma unroll
        for (int j = 1; j < 4; ++j) local = umin64(local, vals[tid + j * 256]);
        red[tid] = local;
        __syncthreads();
        for (int s = 128; s > 0; s >>= 1) {
            if (tid < s) red[tid] = umin64(red[tid], red[tid + s]);
            __syncthreads();
        }
        ull win = red[0];
        if (tid == 0) cand[(b * 32 + ch) * KNN + k] = win;
        #pragma unroll
        for (int j = 0; j < 4; ++j)
            if (vals[tid + j * 256] == win) vals[tid + j * 256] = ~0ull;
        __syncthreads();
    }
}

// ---------------------------------------------------------------------------
// Kernel 4b: per-batch final top-9 from 288 candidates + rescore
// ---------------------------------------------------------------------------
__global__ __launch_bounds__(256) void topk_final_kernel(
    const ull* __restrict__ cand,
    const float* __restrict__ emb, const float* __restrict__ bank,
    const float* __restrict__ x2, const float* __restrict__ y2,
    const float* __restrict__ bscore, const int* __restrict__ bmaxp,
    float* __restrict__ out)
{
    __shared__ ull vals[512];
    __shared__ ull red[256];
    __shared__ int chosen[KNN];
    __shared__ float dists[KNN];
    const int tid = threadIdx.x;
    const int b = blockIdx.x;

    vals[tid]       = (tid < 32 * KNN) ? cand[b * 32 * KNN + tid] : ~0ull;
    vals[tid + 256] = (tid + 256 < 32 * KNN) ? cand[b * 32 * KNN + tid + 256] : ~0ull;
    __syncthreads();

    for (int k = 0; k < KNN; ++k) {
        red[tid] = umin64(vals[tid], vals[tid + 256]);
        __syncthreads();
        for (int s = 128; s > 0; s >>= 1) {
            if (tid < s) red[tid] = umin64(red[tid], red[tid + s]);
            __syncthreads();
        }
        ull win = red[0];
        if (tid == 0) chosen[k] = (int)(win & 0xFFFFFFFFu);
        if (vals[tid] == win) vals[tid] = ~0ull;
        if (vals[tid + 256] == win) vals[tid + 256] = ~0ull;
        __syncthreads();
    }

    const int e = b * P_PATCH + bmaxp[b];
    if (tid < KNN) {
        const float* mf = emb + (size_t)e * D_DIM;
        const float* ms = bank + (size_t)chosen[tid] * D_DIM;
        float dot = 0.0f;
        for (int d = 0; d < D_DIM; ++d) dot = fmaf(mf[d], ms[d], dot);
        float d2 = x2[e] - 2.0f * dot + y2[chosen[tid]];
        dists[tid] = sqrtf(fmaxf(d2, 0.0f));
    }
    __syncthreads();
    if (tid == 0) {
        float mx = dists[0];
        for (int k = 1; k < KNN; ++k) mx = fmaxf(mx, dists[k]);
        float s = 0.0f;
        for (int k = 0; k < KNN; ++k) s += expf(dists[k] - mx);
        float w = 1.0f - expf(dists[0] - mx) / s;
        out[b] = w * bscore[b];
    }
}

// ---------------------------------------------------------------------------
// Kernel 5: fully-fused resize + separable Gaussian blur (exact regroup).
// ---------------------------------------------------------------------------
__device__ __forceinline__ int refl224(int i) {
    if (i < 0) i = -i;
    if (i >= OUT_WH) i = 2 * (OUT_WH - 1) - i;
    return i;
}

__global__ __launch_bounds__(256) void blur_fused_kernel(
    const float* __restrict__ pscore, float* __restrict__ outp)
{
    __shared__ float g[KSIZE];
    __shared__ float ps[P_PATCH];
    __shared__ float q[GRID_WH * OUT_WH];
    __shared__ float hq[GRID_WH * OUT_WH];
    __shared__ float wrow[32][GRID_WH];

    const int tid = threadIdx.x;
    const int band = blockIdx.x;      // 0..6
    const int b    = blockIdx.y;      // 0..7

    if (tid < KSIZE) {
        float x = (tid - KRAD) * 0.25f;
        g[tid] = __expf(-0.5f * x * x);
    }
    for (int i = tid; i < P_PATCH; i += 256) ps[i] = pscore[b * P_PATCH + i];
    __syncthreads();
    if (tid == 0) {
        float s = 0.0f;
        for (int i = 0; i < KSIZE; ++i) s += g[i];
        float inv = 1.0f / s;
        for (int i = 0; i < KSIZE; ++i) g[i] *= inv;
    }
    __syncthreads();

    for (int i = tid; i < GRID_WH * OUT_WH; i += 256) {
        int gy = i / OUT_WH, x = i - gy * OUT_WH;
        float cx = (2 * x - 7) * 0.0625f;
        int ix = (int)floorf(cx); float fx = cx - ix;
        int x0 = min(max(ix, 0), GRID_WH - 1), x1 = min(max(ix + 1, 0), GRID_WH - 1);
        q[i] = ps[gy * GRID_WH + x0] * (1.0f - fx) + ps[gy * GRID_WH + x1] * fx;
    }

    if (tid < 32) {
        int y = band * 32 + tid;
        for (int gy = 0; gy < GRID_WH; ++gy) wrow[tid][gy] = 0.0f;
        for (int t = 0; t < KSIZE; ++t) {
            int yy = refl224(y - KRAD + t);
            float cy = (2 * yy - 7) * 0.0625f;
            int iy = (int)floorf(cy); float fy = cy - iy;
            int y0 = min(max(iy, 0), GRID_WH - 1), y1 = min(max(iy + 1, 0), GRID_WH - 1);
            wrow[tid][y0] += g[t] * (1.0f - fy);
            wrow[tid][y1] += g[t] * fy;
        }
    }
    __syncthreads();

    for (int i = tid; i < GRID_WH * OUT_WH; i += 256) {
        int gy = i / OUT_WH, x = i - gy * OUT_WH;
        float s = 0.0f;
        #pragma unroll
        for (int t = 0; t < KSIZE; ++t)
            s = fmaf(g[t], q[gy * OUT_WH + refl224(x - KRAD + t)], s);
        hq[i] = s;
    }
    __syncthreads();

    const int yl = tid >> 3;                 // 0..31
    const int xbase = (tid & 7) * 28;        // 8 groups x 28 px = 224
    const int y = band * 32 + yl;
    float* orow = outp + ((size_t)b * OUT_WH + y) * OUT_WH;
    for (int i = 0; i < 28; ++i) {
        int x = xbase + i;
        float s = 0.0f;
        #pragma unroll
        for (int gy = 0; gy < GRID_WH; ++gy)
            s = fmaf(wrow[yl][gy], hq[gy * OUT_WH + x], s);
        orow[x] = s;
    }
}

// ---------------------------------------------------------------------------
extern "C" void kernel_launch(void* const* d_in, const int* in_sizes, int n_in,
                              void* d_out, int out_size, void* d_ws, size_t ws_size,
                              hipStream_t stream) {
    const float* emb  = (const float*)d_in[0];
    const float* bank = (const float*)d_in[1];
    float* out = (float*)d_out;

    char* ws = (char*)d_ws;
    ull*   minpack = (ull*)(ws + WS_MINPACK);
    float* x2      = (float*)(ws + WS_X2);
    float* y2      = (float*)(ws + WS_Y2);
    float* pscore  = (float*)(ws + WS_PSCORE);
    float* bscore  = (float*)(ws + WS_BSCORE);
    int*   bmaxp   = (int*)(ws + WS_BMAXP);
    int*   bnn     = (int*)(ws + WS_BNN);
    float* dnn     = (float*)(ws + WS_DNN);
    unsigned short* Apk = (unsigned short*)(ws + WS_APK);
    unsigned short* Bpk = (unsigned short*)(ws + WS_BPK);
    ull*   cand    = (ull*)(ws + WS_CAND);

    // 0: split-pack + sumsq + minpack init (one wave per row)
    prep_kernel<<<(N_EMB + M_BANK) / 4, 256, 0, stream>>>(emb, bank, Apk, Bpk, x2, y2, minpack);
    // 1: MFMA distance + fused min/argmin (2-D grid; 128x256 block tile)
    {
        dim3 grid(M_BANK / 256, N_EMB / 128);   // 128 x 49
        mfma_min_kernel<<<grid, 256, 0, stream>>>(Apk, Bpk, x2, y2, minpack);
    }
    // 2: per-batch argmax (+ pscore unpack)
    batch_argmax_kernel<<<BATCH, 256, 0, stream>>>(minpack, pscore, bscore, bmaxp, bnn);
    // 3: d_nn
    dnn_kernel<<<M_BANK / 4, 256, 0, stream>>>(bank, y2, bnn, dnn);
    // 4a: per-chunk top-9 candidates
    {
        dim3 grid(32, BATCH);
        topk_part_kernel<<<grid, 256, 0, stream>>>(dnn, cand);
    }
    // 4b: final top-9 + rescore -> out[0..7]
    topk_final_kernel<<<BATCH, 256, 0, stream>>>(cand, emb, bank, x2, y2, bscore, bmaxp, out);
    // 5: fused resize + full separable blur -> out[8..]
    {
        dim3 grid(OUT_WH / 32, BATCH);
        blur_fused_kernel<<<grid, 256, 0, stream>>>(pscore, out + BATCH);
    }
}

// Round 4
// 291.092 us; speedup vs baseline: 1.4104x; 1.1090x over previous
//
#include <hip/hip_runtime.h>
#include <hip/hip_bf16.h>

// Problem constants (from setup_inputs)
#define N_EMB   6272
#define M_BANK  32768
#define D_DIM   128
#define KPA     256      // A packed: [hi(128) | lo(128)]
#define KPB     128      // B packed: [hi(128)]
#define BATCH   8
#define P_PATCH 784      // 6272 / 8
#define GRID_WH 28
#define OUT_WH  224
#define KNN     9
#define KSIZE   33
#define KRAD    16

typedef unsigned long long ull;
typedef short bf16x8 __attribute__((ext_vector_type(8)));
typedef float f32x4  __attribute__((ext_vector_type(4)));

// ---------------- workspace layout (bytes), ws ~256 MB ----------------
#define WS_MINPACK 0          // u64[6272]            -> 50176
#define WS_X2      50176      // f32[6272]            -> 75264
#define WS_Y2      75264      // f32[32768]           -> 206336
#define WS_PSCORE  206336     // f32[6272]            -> 231424
#define WS_BSCORE  231424     // f32[8]
#define WS_BMAXP   231456     // i32[8]
#define WS_BNN     231488     // i32[8]
#define WS_DNN     231552     // f32[8*32768]         -> 1280128
#define WS_APK     2885888    // u16[6272*256]        -> 6097408   (16B aligned)
#define WS_BPK     7702784    // u16[32768*128]       -> 16091392  (16B aligned)
#define WS_CAND    32868608   // u64[8*32*9]          -> 32887040

__device__ __forceinline__ ull umin64(ull a, ull b) { return a < b ? a : b; }
__device__ __forceinline__ ull umax64(ull a, ull b) { return a > b ? a : b; }

__device__ __forceinline__ void gload_lds16(const void* g, void* l) {
    __builtin_amdgcn_global_load_lds(
        (const __attribute__((address_space(1))) void*)g,
        (__attribute__((address_space(3))) void*)l, 16, 0, 0);
}

// ---------------------------------------------------------------------------
// Kernel 0 (prep): per-row bf16 hi/lo split-pack + sum-of-squares + minpack init.
// One wave per row. A rows: [hi|lo] (K=256); B rows: [hi] (K=128).
// dot(A_pack, B_pack) over K=256 with B's hi panel reused = (hi_a+lo_a)*hi_b
// = a*hi_b to ~17-bit precision; missing a*lo_b term ~0.018 in d2 (negligible
// vs d2~200, sqrt err ~8e-4).
// ---------------------------------------------------------------------------
__global__ __launch_bounds__(256) void prep_kernel(
    const float* __restrict__ emb, const float* __restrict__ bank,
    unsigned short* __restrict__ Apk, unsigned short* __restrict__ Bpk,
    float* __restrict__ x2, float* __restrict__ y2, ull* __restrict__ minpack)
{
    const int tid = threadIdx.x;
    int gi = blockIdx.x * 256 + tid;
    if (gi < N_EMB) minpack[gi] = ~0ull;

    const int w    = blockIdx.x * 4 + (tid >> 6);
    const int lane = tid & 63;

    float2 v;
    float s;
    if (w < N_EMB) {
        const float* src = emb + (size_t)w * D_DIM;
        v = *(const float2*)&src[2 * lane];
        __hip_bfloat16 h0 = __float2bfloat16(v.x);
        __hip_bfloat16 h1 = __float2bfloat16(v.y);
        __hip_bfloat16 l0 = __float2bfloat16(v.x - __bfloat162float(h0));
        __hip_bfloat16 l1 = __float2bfloat16(v.y - __bfloat162float(h1));
        unsigned hb0 = *(unsigned short*)&h0, hb1 = *(unsigned short*)&h1;
        unsigned lb0 = *(unsigned short*)&l0, lb1 = *(unsigned short*)&l1;
        unsigned short* dst = Apk + (size_t)w * KPA;
        *(unsigned*)&dst[2 * lane]       = hb0 | (hb1 << 16);
        *(unsigned*)&dst[128 + 2 * lane] = lb0 | (lb1 << 16);
        s = fmaf(v.x, v.x, v.y * v.y);
        #pragma unroll
        for (int off = 32; off > 0; off >>= 1) s += __shfl_down(s, off, 64);
        if (lane == 0) x2[w] = s;
    } else {
        int m = w - N_EMB;             // grid sized exactly -> m < M_BANK
        const float* src = bank + (size_t)m * D_DIM;
        v = *(const float2*)&src[2 * lane];
        __hip_bfloat16 h0 = __float2bfloat16(v.x);
        __hip_bfloat16 h1 = __float2bfloat16(v.y);
        unsigned hb0 = *(unsigned short*)&h0, hb1 = *(unsigned short*)&h1;
        unsigned short* dst = Bpk + (size_t)m * KPB;
        *(unsigned*)&dst[2 * lane] = hb0 | (hb1 << 16);
        s = fmaf(v.x, v.x, v.y * v.y);
        #pragma unroll
        for (int off = 32; off > 0; off >>= 1) s += __shfl_down(s, off, 64);
        if (lane == 0) y2[m] = s;
    }
}

// ---------------------------------------------------------------------------
// Kernel 1: MFMA distance + fused min/argmin.
// 128x128 tile, 16x16x32 bf16 MFMA. K restructured into 4 super-chunks:
// each stages {A-hi, A-lo, B-hi} chunk c once and runs 32 MFMAs
// (hi x B and lo x B into the same acc) -> B frags/staging shared by both
// K-panels: 192 ds_read_b128 + 96 staging wave-writes per block (half of
// the K=384 version), same acc[4][4] register footprint (3 waves/SIMD).
// XOR bank-swizzle as before (key=(ra>>1)&3), 0 conflicts.
// LDS 48 KB: 2 bufs x {Ahi[128*32] Alo[128*32] B[128*32]}; epilogue
// red2[128][32] overlays the front 32 KB.
// ---------------------------------------------------------------------------
__global__ __launch_bounds__(256) void mfma_min_kernel(
    const unsigned short* __restrict__ Apk, const unsigned short* __restrict__ Bpk,
    const float* __restrict__ x2, const float* __restrict__ y2,
    ull* __restrict__ minpack)
{
    __shared__ __align__(16) unsigned short smem[2 * 3 * 128 * 32];  // 48 KB
    const int BUFE = 3 * 128 * 32;   // 12288 elems / buffer
    const int ALO  = 128 * 32;       // A-lo panel offset within buffer
    const int BOF  = 2 * 128 * 32;   // B panel offset within buffer

    const int tid  = threadIdx.x;
    const int lane = tid & 63;
    const int wave = tid >> 6;
    const int wr = wave >> 1, wc = wave & 1;
    const int n0 = blockIdx.y * 128;
    const int m0 = blockIdx.x * 128;

    const int srow = tid >> 2;   // 0..63 staging base row
    const int sseg = tid & 3;    // 16B segment (LDS phys)
    const int ssw  = sseg ^ ((srow >> 1) & 3);   // swizzled GLOBAL segment

    const int qa = lane >> 4;    // k-quad (logical)
    const int ra = lane & 15;    // row-in-frag / col-in-C
    const int qsw = qa ^ ((ra >> 1) & 3);        // swizzled LDS segment to read

    f32x4 acc[4][4];
    #pragma unroll
    for (int i = 0; i < 4; ++i)
        #pragma unroll
        for (int j = 0; j < 4; ++j)
            acc[i][j] = (f32x4){0.f, 0.f, 0.f, 0.f};

    const unsigned short* gAh = Apk + (size_t)(n0 + srow) * KPA + ssw * 8;  // hi cols
    const unsigned short* gAl = gAh + 128;                                  // lo cols
    const unsigned short* gB  = Bpk + (size_t)(m0 + srow) * KPB + ssw * 8;
    const int lof0 = srow * 32 + sseg * 8;            // linear LDS dests
    const int lof1 = (srow + 64) * 32 + sseg * 8;

    // prologue: super-chunk 0 -> buffer 0 (6 loads)
    gload_lds16(gAh,             &smem[lof0]);
    gload_lds16(gAh + 64 * KPA,  &smem[lof1]);
    gload_lds16(gAl,             &smem[ALO + lof0]);
    gload_lds16(gAl + 64 * KPA,  &smem[ALO + lof1]);
    gload_lds16(gB,              &smem[BOF + lof0]);
    gload_lds16(gB + 64 * KPB,   &smem[BOF + lof1]);

    for (int c = 0; c < 4; ++c) {
        const int cur = c & 1;
        const int nxt = cur ^ 1;
        // barrier#1: everyone is done reading buf[nxt] (cur of iter c-1)
        asm volatile("s_barrier" ::: "memory");
        if (c < 3) {
            const int ko = (c + 1) * 32;
            gload_lds16(gAh + ko,            &smem[nxt * BUFE + lof0]);
            gload_lds16(gAh + ko + 64 * KPA, &smem[nxt * BUFE + lof1]);
            gload_lds16(gAl + ko,            &smem[nxt * BUFE + ALO + lof0]);
            gload_lds16(gAl + ko + 64 * KPA, &smem[nxt * BUFE + ALO + lof1]);
            gload_lds16(gB + ko,             &smem[nxt * BUFE + BOF + lof0]);
            gload_lds16(gB + ko + 64 * KPB,  &smem[nxt * BUFE + BOF + lof1]);
            // 6 newest (prefetch) may remain in flight; cur's 6 are older
            asm volatile("s_waitcnt vmcnt(6)" ::: "memory");
        } else {
            asm volatile("s_waitcnt vmcnt(0)" ::: "memory");
        }
        // barrier#2: buf[cur] complete in every wave
        asm volatile("s_barrier" ::: "memory");

        const unsigned short* Ah = &smem[cur * BUFE];
        const unsigned short* Al = Ah + ALO;
        const unsigned short* Bs = Ah + BOF;
        bf16x8 afh[4], afl[4], bfr[4];
        #pragma unroll
        for (int i = 0; i < 4; ++i) {
            const int ro = (wr * 64 + i * 16 + ra) * 32 + qsw * 8;
            afh[i] = *(const bf16x8*)&Ah[ro];
            afl[i] = *(const bf16x8*)&Al[ro];
        }
        #pragma unroll
        for (int j = 0; j < 4; ++j)
            bfr[j] = *(const bf16x8*)&Bs[(wc * 64 + j * 16 + ra) * 32 + qsw * 8];
        #pragma unroll
        for (int i = 0; i < 4; ++i)
            #pragma unroll
            for (int j = 0; j < 4; ++j)
                acc[i][j] = __builtin_amdgcn_mfma_f32_16x16x32_bf16(afh[i], bfr[j], acc[i][j], 0, 0, 0);
        #pragma unroll
        for (int i = 0; i < 4; ++i)
            #pragma unroll
            for (int j = 0; j < 4; ++j)
                acc[i][j] = __builtin_amdgcn_mfma_f32_16x16x32_bf16(afl[i], bfr[j], acc[i][j], 0, 0, 0);
    }

    // ---- epilogue: d2 = x2 + y2 - 2*dot, clamp, pack, LDS transpose-reduce ----
    float y2v[4];
    #pragma unroll
    for (int j = 0; j < 4; ++j) y2v[j] = y2[m0 + wc * 64 + j * 16 + ra];

    ull (*red2)[32] = (ull (*)[32])smem;   // 128 rows x 32 (wc*16+ra) = 32 KB

    // all waves must be done reading the K-tiles before red2 overwrites them
    __syncthreads();

    #pragma unroll
    for (int i = 0; i < 4; ++i) {
        #pragma unroll
        for (int r = 0; r < 4; ++r) {
            const int rowl = wr * 64 + i * 16 + qa * 4 + r;
            const float xv = x2[n0 + rowl];
            ull mn = ~0ull;
            #pragma unroll
            for (int j = 0; j < 4; ++j) {
                const int m = m0 + wc * 64 + j * 16 + ra;
                float d2 = fmaf(-2.0f, acc[i][j][r], xv + y2v[j]);
                d2 = fmaxf(d2, 0.0f);
                ull p = ((ull)__float_as_uint(d2) << 32) | (unsigned)m;
                mn = umin64(mn, p);
            }
            red2[rowl][wc * 16 + ra] = mn;
        }
    }
    __syncthreads();
    if (tid < 128) {
        const int l = tid & 63;
        ull mn = ~0ull;
        #pragma unroll
        for (int k = 0; k < 32; ++k)     // lane-staggered cols: distinct bank pairs
            mn = umin64(mn, red2[tid][(k + l) & 31]);
        atomicMin(&minpack[n0 + tid], mn);
    }
}

// ---------------------------------------------------------------------------
// Kernel 2: per-batch argmax of patch scores (fused unpack; argmax over d2
// == argmax over sqrt(d2)); writes pscore for the blur path.
// ---------------------------------------------------------------------------
__global__ __launch_bounds__(256) void batch_argmax_kernel(
    const ull* __restrict__ minpack, float* __restrict__ pscore,
    float* __restrict__ bscore, int* __restrict__ bmaxp, int* __restrict__ bnn)
{
    __shared__ ull red[256];
    int b = blockIdx.x, tid = threadIdx.x;
    ull local = 0;
    for (int p = tid; p < P_PATCH; p += 256) {
        ull mp = minpack[b * P_PATCH + p];
        unsigned d2b = (unsigned)(mp >> 32);
        pscore[b * P_PATCH + p] = sqrtf(__uint_as_float(d2b));
        ull pk = ((ull)d2b << 32) | (unsigned)(p ^ 0xFFFFFFFFu);
        local = umax64(local, pk);
    }
    red[tid] = local;
    __syncthreads();
    for (int s = 128; s > 0; s >>= 1) {
        if (tid < s) red[tid] = umax64(red[tid], red[tid + s]);
        __syncthreads();
    }
    if (tid == 0) {
        ull r = red[0];
        int p = (int)(((unsigned)(r & 0xFFFFFFFFu)) ^ 0xFFFFFFFFu);
        bscore[b] = sqrtf(__uint_as_float((unsigned)(r >> 32)));
        bmaxp[b]  = p;
        bnn[b]    = (int)(minpack[b * P_PATCH + p] & 0xFFFFFFFFu);
    }
}

// ---------------------------------------------------------------------------
// Kernel 3: d_nn = dist(nn_sample[b], memory_bank) -> (8, M)
// ---------------------------------------------------------------------------
__global__ __launch_bounds__(256) void dnn_kernel(
    const float* __restrict__ bank, const float* __restrict__ y2,
    const int* __restrict__ bnn, float* __restrict__ dnn)
{
    __shared__ float nn[BATCH][D_DIM];
    __shared__ float nny2[BATCH];
    int tid = threadIdx.x;
    for (int i = tid; i < BATCH * D_DIM; i += 256) {
        int b = i >> 7, d = i & 127;
        nn[b][d] = bank[(size_t)bnn[b] * D_DIM + d];
    }
    if (tid < BATCH) nny2[tid] = y2[bnn[tid]];
    __syncthreads();

    int w = tid >> 6, lane = tid & 63;
    int m = blockIdx.x * 4 + w;
    float2 v = *(const float2*)&bank[(size_t)m * D_DIM + 2 * lane];
    float part[BATCH];
    #pragma unroll
    for (int b = 0; b < BATCH; ++b)
        part[b] = fmaf(v.x, nn[b][2 * lane], v.y * nn[b][2 * lane + 1]);
    #pragma unroll
    for (int b = 0; b < BATCH; ++b) {
        float s = part[b];
        #pragma unroll
        for (int off = 32; off > 0; off >>= 1) s += __shfl_down(s, off, 64);
        if (lane == 0) {
            float d2 = nny2[b] + y2[m] - 2.0f * s;
            dnn[b * M_BANK + m] = sqrtf(fmaxf(d2, 0.0f));
        }
    }
}

// ---------------------------------------------------------------------------
// Kernel 4a: per-(batch, 1024-chunk) local top-9 of d_nn.
// ---------------------------------------------------------------------------
__global__ __launch_bounds__(256) void topk_part_kernel(
    const float* __restrict__ dnn, ull* __restrict__ cand)
{
    __shared__ ull vals[1024];
    __shared__ ull red[256];
    const int tid = threadIdx.x;
    const int b = blockIdx.y, ch = blockIdx.x;
    const int base = ch * 1024;

    #pragma unroll
    for (int j = 0; j < 4; ++j) {
        int i = base + tid + j * 256;
        vals[tid + j * 256] = ((ull)__float_as_uint(dnn[b * M_BANK + i]) << 32) | (unsigned)i;
    }
    __syncthreads();

    for (int k = 0; k < KNN; ++k) {
        ull local = vals[tid];
        #pragma unroll
        for (int j = 1; j < 4; ++j) local = umin64(local, vals[tid + j * 256]);
        red[tid] = local;
        __syncthreads();
        for (int s = 128; s > 0; s >>= 1) {
            if (tid < s) red[tid] = umin64(red[tid], red[tid + s]);
            __syncthreads();
        }
        ull win = red[0];
        if (tid == 0) cand[(b * 32 + ch) * KNN + k] = win;
        #pragma unroll
        for (int j = 0; j < 4; ++j)
            if (vals[tid + j * 256] == win) vals[tid + j * 256] = ~0ull;
        __syncthreads();
    }
}

// ---------------------------------------------------------------------------
// Kernel 4b: per-batch final top-9 from 288 candidates + rescore
// ---------------------------------------------------------------------------
__global__ __launch_bounds__(256) void topk_final_kernel(
    const ull* __restrict__ cand,
    const float* __restrict__ emb, const float* __restrict__ bank,
    const float* __restrict__ x2, const float* __restrict__ y2,
    const float* __restrict__ bscore, const int* __restrict__ bmaxp,
    float* __restrict__ out)
{
    __shared__ ull vals[512];
    __shared__ ull red[256];
    __shared__ int chosen[KNN];
    __shared__ float dists[KNN];
    const int tid = threadIdx.x;
    const int b = blockIdx.x;

    vals[tid]       = (tid < 32 * KNN) ? cand[b * 32 * KNN + tid] : ~0ull;
    vals[tid + 256] = (tid + 256 < 32 * KNN) ? cand[b * 32 * KNN + tid + 256] : ~0ull;
    __syncthreads();

    for (int k = 0; k < KNN; ++k) {
        red[tid] = umin64(vals[tid], vals[tid + 256]);
        __syncthreads();
        for (int s = 128; s > 0; s >>= 1) {
            if (tid < s) red[tid] = umin64(red[tid], red[tid + s]);
            __syncthreads();
        }
        ull win = red[0];
        if (tid == 0) chosen[k] = (int)(win & 0xFFFFFFFFu);
        if (vals[tid] == win) vals[tid] = ~0ull;
        if (vals[tid + 256] == win) vals[tid + 256] = ~0ull;
        __syncthreads();
    }

    const int e = b * P_PATCH + bmaxp[b];
    if (tid < KNN) {
        const float* mf = emb + (size_t)e * D_DIM;
        const float* ms = bank + (size_t)chosen[tid] * D_DIM;
        float dot = 0.0f;
        for (int d = 0; d < D_DIM; ++d) dot = fmaf(mf[d], ms[d], dot);
        float d2 = x2[e] - 2.0f * dot + y2[chosen[tid]];
        dists[tid] = sqrtf(fmaxf(d2, 0.0f));
    }
    __syncthreads();
    if (tid == 0) {
        float mx = dists[0];
        for (int k = 1; k < KNN; ++k) mx = fmaxf(mx, dists[k]);
        float s = 0.0f;
        for (int k = 0; k < KNN; ++k) s += expf(dists[k] - mx);
        float w = 1.0f - expf(dists[0] - mx) / s;
        out[b] = w * bscore[b];
    }
}

// ---------------------------------------------------------------------------
// Kernel 5: fully-fused resize + separable Gaussian blur (exact regroup).
// ---------------------------------------------------------------------------
__device__ __forceinline__ int refl224(int i) {
    if (i < 0) i = -i;
    if (i >= OUT_WH) i = 2 * (OUT_WH - 1) - i;
    return i;
}

__global__ __launch_bounds__(256) void blur_fused_kernel(
    const float* __restrict__ pscore, float* __restrict__ outp)
{
    __shared__ float g[KSIZE];
    __shared__ float ps[P_PATCH];
    __shared__ float q[GRID_WH * OUT_WH];
    __shared__ float hq[GRID_WH * OUT_WH];
    __shared__ float wrow[32][GRID_WH];

    const int tid = threadIdx.x;
    const int band = blockIdx.x;      // 0..6
    const int b    = blockIdx.y;      // 0..7

    if (tid < KSIZE) {
        float x = (tid - KRAD) * 0.25f;
        g[tid] = __expf(-0.5f * x * x);
    }
    for (int i = tid; i < P_PATCH; i += 256) ps[i] = pscore[b * P_PATCH + i];
    __syncthreads();
    if (tid == 0) {
        float s = 0.0f;
        for (int i = 0; i < KSIZE; ++i) s += g[i];
        float inv = 1.0f / s;
        for (int i = 0; i < KSIZE; ++i) g[i] *= inv;
    }
    __syncthreads();

    for (int i = tid; i < GRID_WH * OUT_WH; i += 256) {
        int gy = i / OUT_WH, x = i - gy * OUT_WH;
        float cx = (2 * x - 7) * 0.0625f;
        int ix = (int)floorf(cx); float fx = cx - ix;
        int x0 = min(max(ix, 0), GRID_WH - 1), x1 = min(max(ix + 1, 0), GRID_WH - 1);
        q[i] = ps[gy * GRID_WH + x0] * (1.0f - fx) + ps[gy * GRID_WH + x1] * fx;
    }

    if (tid < 32) {
        int y = band * 32 + tid;
        for (int gy = 0; gy < GRID_WH; ++gy) wrow[tid][gy] = 0.0f;
        for (int t = 0; t < KSIZE; ++t) {
            int yy = refl224(y - KRAD + t);
            float cy = (2 * yy - 7) * 0.0625f;
            int iy = (int)floorf(cy); float fy = cy - iy;
            int y0 = min(max(iy, 0), GRID_WH - 1), y1 = min(max(iy + 1, 0), GRID_WH - 1);
            wrow[tid][y0] += g[t] * (1.0f - fy);
            wrow[tid][y1] += g[t] * fy;
        }
    }
    __syncthreads();

    for (int i = tid; i < GRID_WH * OUT_WH; i += 256) {
        int gy = i / OUT_WH, x = i - gy * OUT_WH;
        float s = 0.0f;
        #pragma unroll
        for (int t = 0; t < KSIZE; ++t)
            s = fmaf(g[t], q[gy * OUT_WH + refl224(x - KRAD + t)], s);
        hq[i] = s;
    }
    __syncthreads();

    const int yl = tid >> 3;                 // 0..31
    const int xbase = (tid & 7) * 28;        // 8 groups x 28 px = 224
    const int y = band * 32 + yl;
    float* orow = outp + ((size_t)b * OUT_WH + y) * OUT_WH;
    for (int i = 0; i < 28; ++i) {
        int x = xbase + i;
        float s = 0.0f;
        #pragma unroll
        for (int gy = 0; gy < GRID_WH; ++gy)
            s = fmaf(wrow[yl][gy], hq[gy * OUT_WH + x], s);
        orow[x] = s;
    }
}

// ---------------------------------------------------------------------------
extern "C" void kernel_launch(void* const* d_in, const int* in_sizes, int n_in,
                              void* d_out, int out_size, void* d_ws, size_t ws_size,
                              hipStream_t stream) {
    const float* emb  = (const float*)d_in[0];
    const float* bank = (const float*)d_in[1];
    float* out = (float*)d_out;

    char* ws = (char*)d_ws;
    ull*   minpack = (ull*)(ws + WS_MINPACK);
    float* x2      = (float*)(ws + WS_X2);
    float* y2      = (float*)(ws + WS_Y2);
    float* pscore  = (float*)(ws + WS_PSCORE);
    float* bscore  = (float*)(ws + WS_BSCORE);
    int*   bmaxp   = (int*)(ws + WS_BMAXP);
    int*   bnn     = (int*)(ws + WS_BNN);
    float* dnn     = (float*)(ws + WS_DNN);
    unsigned short* Apk = (unsigned short*)(ws + WS_APK);
    unsigned short* Bpk = (unsigned short*)(ws + WS_BPK);
    ull*   cand    = (ull*)(ws + WS_CAND);

    // 0: split-pack + sumsq + minpack init (one wave per row)
    prep_kernel<<<(N_EMB + M_BANK) / 4, 256, 0, stream>>>(emb, bank, Apk, Bpk, x2, y2, minpack);
    // 1: MFMA distance + fused min/argmin (2-D grid; 128x128 tile, K=256 shared-B)
    {
        dim3 grid(M_BANK / 128, N_EMB / 128);   // 256 x 49
        mfma_min_kernel<<<grid, 256, 0, stream>>>(Apk, Bpk, x2, y2, minpack);
    }
    // 2: per-batch argmax (+ pscore unpack)
    batch_argmax_kernel<<<BATCH, 256, 0, stream>>>(minpack, pscore, bscore, bmaxp, bnn);
    // 3: d_nn
    dnn_kernel<<<M_BANK / 4, 256, 0, stream>>>(bank, y2, bnn, dnn);
    // 4a: per-chunk top-9 candidates
    {
        dim3 grid(32, BATCH);
        topk_part_kernel<<<grid, 256, 0, stream>>>(dnn, cand);
    }
    // 4b: final top-9 + rescore -> out[0..7]
    topk_final_kernel<<<BATCH, 256, 0, stream>>>(cand, emb, bank, x2, y2, bscore, bmaxp, out);
    // 5: fused resize + full separable blur -> out[8..]
    {
        dim3 grid(OUT_WH / 32, BATCH);
        blur_fused_kernel<<<grid, 256, 0, stream>>>(pscore, out + BATCH);
    }
}

// Round 5
// 278.412 us; speedup vs baseline: 1.4746x; 1.0455x over previous
//
#include <hip/hip_runtime.h>
#include <hip/hip_bf16.h>

// Problem constants (from setup_inputs)
#define N_EMB   6272
#define M_BANK  32768
#define D_DIM   128
#define KPA     256      // A packed: [hi(128) | lo(128)]
#define KPB     128      // B packed: [hi(128)]
#define BATCH   8
#define P_PATCH 784      // 6272 / 8
#define GRID_WH 28
#define OUT_WH  224
#define KNN     9
#define KSIZE   33
#define KRAD    16

typedef unsigned long long ull;
typedef short bf16x8 __attribute__((ext_vector_type(8)));
typedef float f32x4  __attribute__((ext_vector_type(4)));

// ---------------- workspace layout (bytes), ws ~256 MB ----------------
#define WS_MINPACK 0          // u64[6272]            -> 50176
#define WS_X2      50176      // f32[6272]            -> 75264
#define WS_Y2      75264      // f32[32768]           -> 206336
#define WS_PSCORE  206336     // f32[6272]            -> 231424
#define WS_BSCORE  231424     // f32[8]
#define WS_BMAXP   231456     // i32[8]
#define WS_BNN     231488     // i32[8]
#define WS_DNN     231552     // f32[8*32768]         -> 1280128
#define WS_APK     2885888    // u16[6272*256]        -> 6097408   (16B aligned)
#define WS_BPK     7702784    // u16[32768*128]       -> 16091392  (16B aligned)
#define WS_CAND    32868608   // u64[8*32*9]          -> 32887040

__device__ __forceinline__ ull umin64(ull a, ull b) { return a < b ? a : b; }
__device__ __forceinline__ ull umax64(ull a, ull b) { return a > b ? a : b; }

__device__ __forceinline__ void gload_lds16(const void* g, void* l) {
    __builtin_amdgcn_global_load_lds(
        (const __attribute__((address_space(1))) void*)g,
        (__attribute__((address_space(3))) void*)l, 16, 0, 0);
}

// ---------------------------------------------------------------------------
// Kernel 0 (prep): per-row bf16 hi/lo split-pack + sum-of-squares + minpack init.
// One wave per row. A rows: [hi|lo] (K=256); B rows: [hi] (K=128).
// dot(A_pack, B_pack) with B's hi panel reused = (hi_a+lo_a)*hi_b = a*hi_b
// to ~17-bit precision; missing a*lo_b term ~0.018 in d2 (negligible).
// ---------------------------------------------------------------------------
__global__ __launch_bounds__(256) void prep_kernel(
    const float* __restrict__ emb, const float* __restrict__ bank,
    unsigned short* __restrict__ Apk, unsigned short* __restrict__ Bpk,
    float* __restrict__ x2, float* __restrict__ y2, ull* __restrict__ minpack)
{
    const int tid = threadIdx.x;
    int gi = blockIdx.x * 256 + tid;
    if (gi < N_EMB) minpack[gi] = ~0ull;

    const int w    = blockIdx.x * 4 + (tid >> 6);
    const int lane = tid & 63;

    float2 v;
    float s;
    if (w < N_EMB) {
        const float* src = emb + (size_t)w * D_DIM;
        v = *(const float2*)&src[2 * lane];
        __hip_bfloat16 h0 = __float2bfloat16(v.x);
        __hip_bfloat16 h1 = __float2bfloat16(v.y);
        __hip_bfloat16 l0 = __float2bfloat16(v.x - __bfloat162float(h0));
        __hip_bfloat16 l1 = __float2bfloat16(v.y - __bfloat162float(h1));
        unsigned hb0 = *(unsigned short*)&h0, hb1 = *(unsigned short*)&h1;
        unsigned lb0 = *(unsigned short*)&l0, lb1 = *(unsigned short*)&l1;
        unsigned short* dst = Apk + (size_t)w * KPA;
        *(unsigned*)&dst[2 * lane]       = hb0 | (hb1 << 16);
        *(unsigned*)&dst[128 + 2 * lane] = lb0 | (lb1 << 16);
        s = fmaf(v.x, v.x, v.y * v.y);
        #pragma unroll
        for (int off = 32; off > 0; off >>= 1) s += __shfl_down(s, off, 64);
        if (lane == 0) x2[w] = s;
    } else {
        int m = w - N_EMB;             // grid sized exactly -> m < M_BANK
        const float* src = bank + (size_t)m * D_DIM;
        v = *(const float2*)&src[2 * lane];
        __hip_bfloat16 h0 = __float2bfloat16(v.x);
        __hip_bfloat16 h1 = __float2bfloat16(v.y);
        unsigned hb0 = *(unsigned short*)&h0, hb1 = *(unsigned short*)&h1;
        unsigned short* dst = Bpk + (size_t)m * KPB;
        *(unsigned*)&dst[2 * lane] = hb0 | (hb1 << 16);
        s = fmaf(v.x, v.x, v.y * v.y);
        #pragma unroll
        for (int off = 32; off > 0; off >>= 1) s += __shfl_down(s, off, 64);
        if (lane == 0) y2[m] = s;
    }
}

// ---------------------------------------------------------------------------
// Kernel 1: MFMA distance + fused min/argmin.
// 128x128 tile, K=256 shared-B. NEW: K streamed as 8 half-steps; step s
// stages ONE A panel (hi/lo of chunk s>>1, 8 KB) into A-dbuf; B(c) staged
// only on even steps into B-dbuf; B fragments held in VGPR across the odd
// step. LDS = 32 KB (was 48) -> ~3 blocks/CU resident (reg-bound), restoring
// R2-level occupancy at R4's traffic level. vmcnt per step = count just
// issued {4,2,4,2,4,2,2,0} so the previous step's loads are drained, never
// idling the queue. Same MFMA order as R4 -> bit-identical numerics.
// ---------------------------------------------------------------------------
__global__ __launch_bounds__(256) void mfma_min_kernel(
    const unsigned short* __restrict__ Apk, const unsigned short* __restrict__ Bpk,
    const float* __restrict__ x2, const float* __restrict__ y2,
    ull* __restrict__ minpack)
{
    __shared__ __align__(16) unsigned short smem[4 * 128 * 32];  // 32 KB
    const int PAN = 128 * 32;   // 4096 elems = 8 KB panel
    // panels: A0=smem[0], A1=smem[PAN], B0=smem[2*PAN], B1=smem[3*PAN]

    const int tid  = threadIdx.x;
    const int lane = tid & 63;
    const int wave = tid >> 6;
    const int wr = wave >> 1, wc = wave & 1;
    const int n0 = blockIdx.y * 128;
    const int m0 = blockIdx.x * 128;

    const int srow = tid >> 2;   // 0..63 staging base row
    const int sseg = tid & 3;    // 16B segment (LDS phys)
    const int ssw  = sseg ^ ((srow >> 1) & 3);   // swizzled GLOBAL segment

    const int qa = lane >> 4;    // k-quad (logical)
    const int ra = lane & 15;    // row-in-frag / col-in-C
    const int qsw = qa ^ ((ra >> 1) & 3);        // swizzled LDS segment to read

    f32x4 acc[4][4];
    #pragma unroll
    for (int i = 0; i < 4; ++i)
        #pragma unroll
        for (int j = 0; j < 4; ++j)
            acc[i][j] = (f32x4){0.f, 0.f, 0.f, 0.f};

    const unsigned short* gA = Apk + (size_t)(n0 + srow) * KPA + ssw * 8;
    const unsigned short* gB = Bpk + (size_t)(m0 + srow) * KPB + ssw * 8;
    const int lof0 = srow * 32 + sseg * 8;            // linear LDS dests
    const int lof1 = (srow + 64) * 32 + sseg * 8;

    // A panel column base for step s: hi/lo interleave. s=0:hi(c0)=0, 1:lo(c0)=128,
    // 2:hi(c1)=32, 3:lo(c1)=160, ... 7:lo(c3)=224.
    #define ACOL(s) ((((s) & 1) * 128) + (((s) >> 1) * 32))

    // prologue: A panel 0 -> A0, B(0) -> B0
    gload_lds16(gA,            &smem[lof0]);
    gload_lds16(gA + 64 * KPA, &smem[lof1]);
    gload_lds16(gB,            &smem[2 * PAN + lof0]);
    gload_lds16(gB + 64 * KPB, &smem[2 * PAN + lof1]);

    bf16x8 bfr[4];   // B fragments, held across the hi/lo step pair

    #define STEP(s, VM) { \
        /* barrier#1: all waves done reading the buffers we now overwrite */ \
        asm volatile("s_barrier" ::: "memory"); \
        if ((s) < 7) { \
            const int ab = ((s) + 1) & 1; \
            gload_lds16(gA + ACOL((s) + 1),           &smem[ab * PAN + lof0]); \
            gload_lds16(gA + ACOL((s) + 1) + 64 * KPA, &smem[ab * PAN + lof1]); \
        } \
        if (((s) & 1) == 0 && (s) < 6) { \
            const int cn = ((s) >> 1) + 1; \
            const int bb = cn & 1; \
            gload_lds16(gB + cn * 32,            &smem[(2 + bb) * PAN + lof0]); \
            gload_lds16(gB + cn * 32 + 64 * KPB, &smem[(2 + bb) * PAN + lof1]); \
        } \
        /* wait: previous step's loads complete; this step's stay in flight */ \
        asm volatile("s_waitcnt vmcnt(" #VM ")" ::: "memory"); \
        /* barrier#2: current panels complete in every wave */ \
        asm volatile("s_barrier" ::: "memory"); \
        const unsigned short* As = &smem[((s) & 1) * PAN]; \
        bf16x8 af[4]; \
        _Pragma("unroll") \
        for (int i = 0; i < 4; ++i) \
            af[i] = *(const bf16x8*)&As[(wr * 64 + i * 16 + ra) * 32 + qsw * 8]; \
        if (((s) & 1) == 0) { \
            const unsigned short* Bs = &smem[(2 + (((s) >> 1) & 1)) * PAN]; \
            _Pragma("unroll") \
            for (int j = 0; j < 4; ++j) \
                bfr[j] = *(const bf16x8*)&Bs[(wc * 64 + j * 16 + ra) * 32 + qsw * 8]; \
        } \
        _Pragma("unroll") \
        for (int i = 0; i < 4; ++i) \
            _Pragma("unroll") \
            for (int j = 0; j < 4; ++j) \
                acc[i][j] = __builtin_amdgcn_mfma_f32_16x16x32_bf16(af[i], bfr[j], acc[i][j], 0, 0, 0); \
    }

    STEP(0, 4) STEP(1, 2) STEP(2, 4) STEP(3, 2)
    STEP(4, 4) STEP(5, 2) STEP(6, 2) STEP(7, 0)
    #undef STEP
    #undef ACOL

    // ---- epilogue: d2 = x2 + y2 - 2*dot, clamp, pack, LDS transpose-reduce ----
    float y2v[4];
    #pragma unroll
    for (int j = 0; j < 4; ++j) y2v[j] = y2[m0 + wc * 64 + j * 16 + ra];

    ull (*red2)[32] = (ull (*)[32])smem;   // 128 rows x 32 = 32 KB (whole smem)

    // all waves must be done reading the K-panels before red2 overwrites them
    __syncthreads();

    #pragma unroll
    for (int i = 0; i < 4; ++i) {
        #pragma unroll
        for (int r = 0; r < 4; ++r) {
            const int rowl = wr * 64 + i * 16 + qa * 4 + r;
            const float xv = x2[n0 + rowl];
            ull mn = ~0ull;
            #pragma unroll
            for (int j = 0; j < 4; ++j) {
                const int m = m0 + wc * 64 + j * 16 + ra;
                float d2 = fmaf(-2.0f, acc[i][j][r], xv + y2v[j]);
                d2 = fmaxf(d2, 0.0f);
                ull p = ((ull)__float_as_uint(d2) << 32) | (unsigned)m;
                mn = umin64(mn, p);
            }
            red2[rowl][wc * 16 + ra] = mn;
        }
    }
    __syncthreads();
    if (tid < 128) {
        const int l = tid & 63;
        ull mn = ~0ull;
        #pragma unroll
        for (int k = 0; k < 32; ++k)     // lane-staggered cols: distinct bank pairs
            mn = umin64(mn, red2[tid][(k + l) & 31]);
        atomicMin(&minpack[n0 + tid], mn);
    }
}

// ---------------------------------------------------------------------------
// Kernel 2: per-batch argmax of patch scores (fused unpack; argmax over d2
// == argmax over sqrt(d2)); writes pscore for the blur path.
// ---------------------------------------------------------------------------
__global__ __launch_bounds__(256) void batch_argmax_kernel(
    const ull* __restrict__ minpack, float* __restrict__ pscore,
    float* __restrict__ bscore, int* __restrict__ bmaxp, int* __restrict__ bnn)
{
    __shared__ ull red[256];
    int b = blockIdx.x, tid = threadIdx.x;
    ull local = 0;
    for (int p = tid; p < P_PATCH; p += 256) {
        ull mp = minpack[b * P_PATCH + p];
        unsigned d2b = (unsigned)(mp >> 32);
        pscore[b * P_PATCH + p] = sqrtf(__uint_as_float(d2b));
        ull pk = ((ull)d2b << 32) | (unsigned)(p ^ 0xFFFFFFFFu);
        local = umax64(local, pk);
    }
    red[tid] = local;
    __syncthreads();
    for (int s = 128; s > 0; s >>= 1) {
        if (tid < s) red[tid] = umax64(red[tid], red[tid + s]);
        __syncthreads();
    }
    if (tid == 0) {
        ull r = red[0];
        int p = (int)(((unsigned)(r & 0xFFFFFFFFu)) ^ 0xFFFFFFFFu);
        bscore[b] = sqrtf(__uint_as_float((unsigned)(r >> 32)));
        bmaxp[b]  = p;
        bnn[b]    = (int)(minpack[b * P_PATCH + p] & 0xFFFFFFFFu);
    }
}

// ---------------------------------------------------------------------------
// Kernel 3: d_nn = dist(nn_sample[b], memory_bank) -> (8, M)
// ---------------------------------------------------------------------------
__global__ __launch_bounds__(256) void dnn_kernel(
    const float* __restrict__ bank, const float* __restrict__ y2,
    const int* __restrict__ bnn, float* __restrict__ dnn)
{
    __shared__ float nn[BATCH][D_DIM];
    __shared__ float nny2[BATCH];
    int tid = threadIdx.x;
    for (int i = tid; i < BATCH * D_DIM; i += 256) {
        int b = i >> 7, d = i & 127;
        nn[b][d] = bank[(size_t)bnn[b] * D_DIM + d];
    }
    if (tid < BATCH) nny2[tid] = y2[bnn[tid]];
    __syncthreads();

    int w = tid >> 6, lane = tid & 63;
    int m = blockIdx.x * 4 + w;
    float2 v = *(const float2*)&bank[(size_t)m * D_DIM + 2 * lane];
    float part[BATCH];
    #pragma unroll
    for (int b = 0; b < BATCH; ++b)
        part[b] = fmaf(v.x, nn[b][2 * lane], v.y * nn[b][2 * lane + 1]);
    #pragma unroll
    for (int b = 0; b < BATCH; ++b) {
        float s = part[b];
        #pragma unroll
        for (int off = 32; off > 0; off >>= 1) s += __shfl_down(s, off, 64);
        if (lane == 0) {
            float d2 = nny2[b] + y2[m] - 2.0f * s;
            dnn[b * M_BANK + m] = sqrtf(fmaxf(d2, 0.0f));
        }
    }
}

// ---------------------------------------------------------------------------
// Kernel 4a: per-(batch, 1024-chunk) local top-9 of d_nn.
// ---------------------------------------------------------------------------
__global__ __launch_bounds__(256) void topk_part_kernel(
    const float* __restrict__ dnn, ull* __restrict__ cand)
{
    __shared__ ull vals[1024];
    __shared__ ull red[256];
    const int tid = threadIdx.x;
    const int b = blockIdx.y, ch = blockIdx.x;
    const int base = ch * 1024;

    #pragma unroll
    for (int j = 0; j < 4; ++j) {
        int i = base + tid + j * 256;
        vals[tid + j * 256] = ((ull)__float_as_uint(dnn[b * M_BANK + i]) << 32) | (unsigned)i;
    }
    __syncthreads();

    for (int k = 0; k < KNN; ++k) {
        ull local = vals[tid];
        #pragma unroll
        for (int j = 1; j < 4; ++j) local = umin64(local, vals[tid + j * 256]);
        red[tid] = local;
        __syncthreads();
        for (int s = 128; s > 0; s >>= 1) {
            if (tid < s) red[tid] = umin64(red[tid], red[tid + s]);
            __syncthreads();
        }
        ull win = red[0];
        if (tid == 0) cand[(b * 32 + ch) * KNN + k] = win;
        #pragma unroll
        for (int j = 0; j < 4; ++j)
            if (vals[tid + j * 256] == win) vals[tid + j * 256] = ~0ull;
        __syncthreads();
    }
}

// ---------------------------------------------------------------------------
// Kernel 4b: per-batch final top-9 from 288 candidates + rescore
// ---------------------------------------------------------------------------
__global__ __launch_bounds__(256) void topk_final_kernel(
    const ull* __restrict__ cand,
    const float* __restrict__ emb, const float* __restrict__ bank,
    const float* __restrict__ x2, const float* __restrict__ y2,
    const float* __restrict__ bscore, const int* __restrict__ bmaxp,
    float* __restrict__ out)
{
    __shared__ ull vals[512];
    __shared__ ull red[256];
    __shared__ int chosen[KNN];
    __shared__ float dists[KNN];
    const int tid = threadIdx.x;
    const int b = blockIdx.x;

    vals[tid]       = (tid < 32 * KNN) ? cand[b * 32 * KNN + tid] : ~0ull;
    vals[tid + 256] = (tid + 256 < 32 * KNN) ? cand[b * 32 * KNN + tid + 256] : ~0ull;
    __syncthreads();

    for (int k = 0; k < KNN; ++k) {
        red[tid] = umin64(vals[tid], vals[tid + 256]);
        __syncthreads();
        for (int s = 128; s > 0; s >>= 1) {
            if (tid < s) red[tid] = umin64(red[tid], red[tid + s]);
            __syncthreads();
        }
        ull win = red[0];
        if (tid == 0) chosen[k] = (int)(win & 0xFFFFFFFFu);
        if (vals[tid] == win) vals[tid] = ~0ull;
        if (vals[tid + 256] == win) vals[tid + 256] = ~0ull;
        __syncthreads();
    }

    const int e = b * P_PATCH + bmaxp[b];
    if (tid < KNN) {
        const float* mf = emb + (size_t)e * D_DIM;
        const float* ms = bank + (size_t)chosen[tid] * D_DIM;
        float dot = 0.0f;
        for (int d = 0; d < D_DIM; ++d) dot = fmaf(mf[d], ms[d], dot);
        float d2 = x2[e] - 2.0f * dot + y2[chosen[tid]];
        dists[tid] = sqrtf(fmaxf(d2, 0.0f));
    }
    __syncthreads();
    if (tid == 0) {
        float mx = dists[0];
        for (int k = 1; k < KNN; ++k) mx = fmaxf(mx, dists[k]);
        float s = 0.0f;
        for (int k = 0; k < KNN; ++k) s += expf(dists[k] - mx);
        float w = 1.0f - expf(dists[0] - mx) / s;
        out[b] = w * bscore[b];
    }
}

// ---------------------------------------------------------------------------
// Kernel 5: fully-fused resize + separable Gaussian blur (exact regroup).
// ---------------------------------------------------------------------------
__device__ __forceinline__ int refl224(int i) {
    if (i < 0) i = -i;
    if (i >= OUT_WH) i = 2 * (OUT_WH - 1) - i;
    return i;
}

__global__ __launch_bounds__(256) void blur_fused_kernel(
    const float* __restrict__ pscore, float* __restrict__ outp)
{
    __shared__ float g[KSIZE];
    __shared__ float ps[P_PATCH];
    __shared__ float q[GRID_WH * OUT_WH];
    __shared__ float hq[GRID_WH * OUT_WH];
    __shared__ float wrow[32][GRID_WH];

    const int tid = threadIdx.x;
    const int band = blockIdx.x;      // 0..6
    const int b    = blockIdx.y;      // 0..7

    if (tid < KSIZE) {
        float x = (tid - KRAD) * 0.25f;
        g[tid] = __expf(-0.5f * x * x);
    }
    for (int i = tid; i < P_PATCH; i += 256) ps[i] = pscore[b * P_PATCH + i];
    __syncthreads();
    if (tid == 0) {
        float s = 0.0f;
        for (int i = 0; i < KSIZE; ++i) s += g[i];
        float inv = 1.0f / s;
        for (int i = 0; i < KSIZE; ++i) g[i] *= inv;
    }
    __syncthreads();

    for (int i = tid; i < GRID_WH * OUT_WH; i += 256) {
        int gy = i / OUT_WH, x = i - gy * OUT_WH;
        float cx = (2 * x - 7) * 0.0625f;
        int ix = (int)floorf(cx); float fx = cx - ix;
        int x0 = min(max(ix, 0), GRID_WH - 1), x1 = min(max(ix + 1, 0), GRID_WH - 1);
        q[i] = ps[gy * GRID_WH + x0] * (1.0f - fx) + ps[gy * GRID_WH + x1] * fx;
    }

    if (tid < 32) {
        int y = band * 32 + tid;
        for (int gy = 0; gy < GRID_WH; ++gy) wrow[tid][gy] = 0.0f;
        for (int t = 0; t < KSIZE; ++t) {
            int yy = refl224(y - KRAD + t);
            float cy = (2 * yy - 7) * 0.0625f;
            int iy = (int)floorf(cy); float fy = cy - iy;
            int y0 = min(max(iy, 0), GRID_WH - 1), y1 = min(max(iy + 1, 0), GRID_WH - 1);
            wrow[tid][y0] += g[t] * (1.0f - fy);
            wrow[tid][y1] += g[t] * fy;
        }
    }
    __syncthreads();

    for (int i = tid; i < GRID_WH * OUT_WH; i += 256) {
        int gy = i / OUT_WH, x = i - gy * OUT_WH;
        float s = 0.0f;
        #pragma unroll
        for (int t = 0; t < KSIZE; ++t)
            s = fmaf(g[t], q[gy * OUT_WH + refl224(x - KRAD + t)], s);
        hq[i] = s;
    }
    __syncthreads();

    const int yl = tid >> 3;                 // 0..31
    const int xbase = (tid & 7) * 28;        // 8 groups x 28 px = 224
    const int y = band * 32 + yl;
    float* orow = outp + ((size_t)b * OUT_WH + y) * OUT_WH;
    for (int i = 0; i < 28; ++i) {
        int x = xbase + i;
        float s = 0.0f;
        #pragma unroll
        for (int gy = 0; gy < GRID_WH; ++gy)
            s = fmaf(wrow[yl][gy], hq[gy * OUT_WH + x], s);
        orow[x] = s;
    }
}

// ---------------------------------------------------------------------------
extern "C" void kernel_launch(void* const* d_in, const int* in_sizes, int n_in,
                              void* d_out, int out_size, void* d_ws, size_t ws_size,
                              hipStream_t stream) {
    const float* emb  = (const float*)d_in[0];
    const float* bank = (const float*)d_in[1];
    float* out = (float*)d_out;

    char* ws = (char*)d_ws;
    ull*   minpack = (ull*)(ws + WS_MINPACK);
    float* x2      = (float*)(ws + WS_X2);
    float* y2      = (float*)(ws + WS_Y2);
    float* pscore  = (float*)(ws + WS_PSCORE);
    float* bscore  = (float*)(ws + WS_BSCORE);
    int*   bmaxp   = (int*)(ws + WS_BMAXP);
    int*   bnn     = (int*)(ws + WS_BNN);
    float* dnn     = (float*)(ws + WS_DNN);
    unsigned short* Apk = (unsigned short*)(ws + WS_APK);
    unsigned short* Bpk = (unsigned short*)(ws + WS_BPK);
    ull*   cand    = (ull*)(ws + WS_CAND);

    // 0: split-pack + sumsq + minpack init (one wave per row)
    prep_kernel<<<(N_EMB + M_BANK) / 4, 256, 0, stream>>>(emb, bank, Apk, Bpk, x2, y2, minpack);
    // 1: MFMA distance + fused min/argmin (2-D grid; 128x128 tile, K=256 shared-B)
    {
        dim3 grid(M_BANK / 128, N_EMB / 128);   // 256 x 49
        mfma_min_kernel<<<grid, 256, 0, stream>>>(Apk, Bpk, x2, y2, minpack);
    }
    // 2: per-batch argmax (+ pscore unpack)
    batch_argmax_kernel<<<BATCH, 256, 0, stream>>>(minpack, pscore, bscore, bmaxp, bnn);
    // 3: d_nn
    dnn_kernel<<<M_BANK / 4, 256, 0, stream>>>(bank, y2, bnn, dnn);
    // 4a: per-chunk top-9 candidates
    {
        dim3 grid(32, BATCH);
        topk_part_kernel<<<grid, 256, 0, stream>>>(dnn, cand);
    }
    // 4b: final top-9 + rescore -> out[0..7]
    topk_final_kernel<<<BATCH, 256, 0, stream>>>(cand, emb, bank, x2, y2, bscore, bmaxp, out);
    // 5: fused resize + full separable blur -> out[8..]
    {
        dim3 grid(OUT_WH / 32, BATCH);
        blur_fused_kernel<<<grid, 256, 0, stream>>>(pscore, out + BATCH);
    }
}

// Round 6
// 276.737 us; speedup vs baseline: 1.4835x; 1.0060x over previous
//
#include <hip/hip_runtime.h>
#include <hip/hip_bf16.h>

// Problem constants (from setup_inputs)
#define N_EMB   6272
#define M_BANK  32768
#define D_DIM   128
#define KPA     256      // A packed: [hi(128) | lo(128)]
#define KPB     128      // B packed: [hi(128)]
#define BATCH   8
#define P_PATCH 784      // 6272 / 8
#define GRID_WH 28
#define OUT_WH  224
#define KNN     9
#define KSIZE   33
#define KRAD    16

typedef unsigned long long ull;
typedef short bf16x8 __attribute__((ext_vector_type(8)));
typedef float f32x4  __attribute__((ext_vector_type(4)));

// ---------------- workspace layout (bytes), ws ~256 MB ----------------
#define WS_MINPACK 0          // u64[6272]            -> 50176
#define WS_X2      50176      // f32[6272]            -> 75264
#define WS_Y2      75264      // f32[32768]           -> 206336
#define WS_PSCORE  206336     // f32[6272]            -> 231424
#define WS_BSCORE  231424     // f32[8]
#define WS_BMAXP   231456     // i32[8]
#define WS_BNN     231488     // i32[8]
#define WS_DNN     231552     // f32[8*32768]         -> 1280128
#define WS_APK     2885888    // u16[6272*256]        -> 6097408   (16B aligned)
#define WS_BPK     7702784    // u16[32768*128]       -> 16091392  (16B aligned)
#define WS_CAND    32868608   // u64[8*32*9]          -> 32887040

__device__ __forceinline__ ull umin64(ull a, ull b) { return a < b ? a : b; }
__device__ __forceinline__ ull umax64(ull a, ull b) { return a > b ? a : b; }

__device__ __forceinline__ void gload_lds16(const void* g, void* l) {
    __builtin_amdgcn_global_load_lds(
        (const __attribute__((address_space(1))) void*)g,
        (__attribute__((address_space(3))) void*)l, 16, 0, 0);
}

// ---------------------------------------------------------------------------
// Kernel 0 (prep): per-row bf16 hi/lo split-pack + sum-of-squares + minpack init.
// One wave per row. A rows: [hi|lo] (K=256); B rows: [hi] (K=128).
// dot(A_pack, B_pack) with B's hi panel reused = (hi_a+lo_a)*hi_b = a*hi_b
// to ~17-bit precision; missing a*lo_b term ~0.018 in d2 (negligible).
// ---------------------------------------------------------------------------
__global__ __launch_bounds__(256) void prep_kernel(
    const float* __restrict__ emb, const float* __restrict__ bank,
    unsigned short* __restrict__ Apk, unsigned short* __restrict__ Bpk,
    float* __restrict__ x2, float* __restrict__ y2, ull* __restrict__ minpack)
{
    const int tid = threadIdx.x;
    int gi = blockIdx.x * 256 + tid;
    if (gi < N_EMB) minpack[gi] = ~0ull;

    const int w    = blockIdx.x * 4 + (tid >> 6);
    const int lane = tid & 63;

    float2 v;
    float s;
    if (w < N_EMB) {
        const float* src = emb + (size_t)w * D_DIM;
        v = *(const float2*)&src[2 * lane];
        __hip_bfloat16 h0 = __float2bfloat16(v.x);
        __hip_bfloat16 h1 = __float2bfloat16(v.y);
        __hip_bfloat16 l0 = __float2bfloat16(v.x - __bfloat162float(h0));
        __hip_bfloat16 l1 = __float2bfloat16(v.y - __bfloat162float(h1));
        unsigned hb0 = *(unsigned short*)&h0, hb1 = *(unsigned short*)&h1;
        unsigned lb0 = *(unsigned short*)&l0, lb1 = *(unsigned short*)&l1;
        unsigned short* dst = Apk + (size_t)w * KPA;
        *(unsigned*)&dst[2 * lane]       = hb0 | (hb1 << 16);
        *(unsigned*)&dst[128 + 2 * lane] = lb0 | (lb1 << 16);
        s = fmaf(v.x, v.x, v.y * v.y);
        #pragma unroll
        for (int off = 32; off > 0; off >>= 1) s += __shfl_down(s, off, 64);
        if (lane == 0) x2[w] = s;
    } else {
        int m = w - N_EMB;             // grid sized exactly -> m < M_BANK
        const float* src = bank + (size_t)m * D_DIM;
        v = *(const float2*)&src[2 * lane];
        __hip_bfloat16 h0 = __float2bfloat16(v.x);
        __hip_bfloat16 h1 = __float2bfloat16(v.y);
        unsigned hb0 = *(unsigned short*)&h0, hb1 = *(unsigned short*)&h1;
        unsigned short* dst = Bpk + (size_t)m * KPB;
        *(unsigned*)&dst[2 * lane] = hb0 | (hb1 << 16);
        s = fmaf(v.x, v.x, v.y * v.y);
        #pragma unroll
        for (int off = 32; off > 0; off >>= 1) s += __shfl_down(s, off, 64);
        if (lane == 0) y2[m] = s;
    }
}

// ---------------------------------------------------------------------------
// Kernel 1: MFMA distance + fused min/argmin.
// 128x128 tile, K=256 shared-B, 8 half-steps (32 KB LDS, A/B dbuf panels).
// R6: (a) __launch_bounds__(256,4): unified regs <=128/wave (acc=64 fixed,
// arch<=64) -> 4 blocks/CU resident (LDS allows 5). (b) epilogue packs
// key = y2[m]+1000 - 2*dot (row-constant x2 dropped -> argmin-equivalent
// per row; +1000 keeps keys positive so float-bit u64 ordering is monotone;
// keys block-consistent for atomicMin). Kills 16 x2 global loads + 64 adds
// + 64 fmax per thread; d2 reconstituted in batch_argmax.
// ---------------------------------------------------------------------------
__global__ __launch_bounds__(256, 4) void mfma_min_kernel(
    const unsigned short* __restrict__ Apk, const unsigned short* __restrict__ Bpk,
    const float* __restrict__ y2, ull* __restrict__ minpack)
{
    __shared__ __align__(16) unsigned short smem[4 * 128 * 32];  // 32 KB
    const int PAN = 128 * 32;   // 4096 elems = 8 KB panel
    // panels: A0=smem[0], A1=smem[PAN], B0=smem[2*PAN], B1=smem[3*PAN]

    const int tid  = threadIdx.x;
    const int lane = tid & 63;
    const int wave = tid >> 6;
    const int wr = wave >> 1, wc = wave & 1;
    const int n0 = blockIdx.y * 128;
    const int m0 = blockIdx.x * 128;

    const int srow = tid >> 2;   // 0..63 staging base row
    const int sseg = tid & 3;    // 16B segment (LDS phys)
    const int ssw  = sseg ^ ((srow >> 1) & 3);   // swizzled GLOBAL segment

    const int qa = lane >> 4;    // k-quad (logical)
    const int ra = lane & 15;    // row-in-frag / col-in-C
    const int qsw = qa ^ ((ra >> 1) & 3);        // swizzled LDS segment to read

    f32x4 acc[4][4];
    #pragma unroll
    for (int i = 0; i < 4; ++i)
        #pragma unroll
        for (int j = 0; j < 4; ++j)
            acc[i][j] = (f32x4){0.f, 0.f, 0.f, 0.f};

    const unsigned short* gA = Apk + (size_t)(n0 + srow) * KPA + ssw * 8;
    const unsigned short* gB = Bpk + (size_t)(m0 + srow) * KPB + ssw * 8;
    const int lof0 = srow * 32 + sseg * 8;            // linear LDS dests
    const int lof1 = (srow + 64) * 32 + sseg * 8;

    // A panel column base for step s: hi/lo interleave.
    #define ACOL(s) ((((s) & 1) * 128) + (((s) >> 1) * 32))

    // prologue: A panel 0 -> A0, B(0) -> B0
    gload_lds16(gA,            &smem[lof0]);
    gload_lds16(gA + 64 * KPA, &smem[lof1]);
    gload_lds16(gB,            &smem[2 * PAN + lof0]);
    gload_lds16(gB + 64 * KPB, &smem[2 * PAN + lof1]);

    bf16x8 bfr[4];   // B fragments, held across the hi/lo step pair

    #define STEP(s, VM) { \
        /* barrier#1: all waves done reading the buffers we now overwrite */ \
        asm volatile("s_barrier" ::: "memory"); \
        if ((s) < 7) { \
            const int ab = ((s) + 1) & 1; \
            gload_lds16(gA + ACOL((s) + 1),            &smem[ab * PAN + lof0]); \
            gload_lds16(gA + ACOL((s) + 1) + 64 * KPA, &smem[ab * PAN + lof1]); \
        } \
        if (((s) & 1) == 0 && (s) < 6) { \
            const int cn = ((s) >> 1) + 1; \
            const int bb = cn & 1; \
            gload_lds16(gB + cn * 32,            &smem[(2 + bb) * PAN + lof0]); \
            gload_lds16(gB + cn * 32 + 64 * KPB, &smem[(2 + bb) * PAN + lof1]); \
        } \
        /* wait: previous step's loads complete; this step's stay in flight */ \
        asm volatile("s_waitcnt vmcnt(" #VM ")" ::: "memory"); \
        /* barrier#2: current panels complete in every wave */ \
        asm volatile("s_barrier" ::: "memory"); \
        const unsigned short* As = &smem[((s) & 1) * PAN]; \
        bf16x8 af[4]; \
        _Pragma("unroll") \
        for (int i = 0; i < 4; ++i) \
            af[i] = *(const bf16x8*)&As[(wr * 64 + i * 16 + ra) * 32 + qsw * 8]; \
        if (((s) & 1) == 0) { \
            const unsigned short* Bs = &smem[(2 + (((s) >> 1) & 1)) * PAN]; \
            _Pragma("unroll") \
            for (int j = 0; j < 4; ++j) \
                bfr[j] = *(const bf16x8*)&Bs[(wc * 64 + j * 16 + ra) * 32 + qsw * 8]; \
        } \
        _Pragma("unroll") \
        for (int i = 0; i < 4; ++i) \
            _Pragma("unroll") \
            for (int j = 0; j < 4; ++j) \
                acc[i][j] = __builtin_amdgcn_mfma_f32_16x16x32_bf16(af[i], bfr[j], acc[i][j], 0, 0, 0); \
    }

    STEP(0, 4) STEP(1, 2) STEP(2, 4) STEP(3, 2)
    STEP(4, 4) STEP(5, 2) STEP(6, 2) STEP(7, 0)
    #undef STEP
    #undef ACOL

    // ---- epilogue: key = y2[m]+1000 - 2*dot; pack; LDS transpose-reduce ----
    float y2k[4];
    unsigned mj[4];
    #pragma unroll
    for (int j = 0; j < 4; ++j) {
        const int m = m0 + wc * 64 + j * 16 + ra;
        y2k[j] = y2[m] + 1000.0f;
        mj[j]  = (unsigned)m;
    }

    ull (*red2)[32] = (ull (*)[32])smem;   // 128 rows x 32 = 32 KB (whole smem)

    // all waves must be done reading the K-panels before red2 overwrites them
    __syncthreads();

    #pragma unroll
    for (int i = 0; i < 4; ++i) {
        #pragma unroll
        for (int r = 0; r < 4; ++r) {
            const int rowl = wr * 64 + i * 16 + qa * 4 + r;
            ull mn = ~0ull;
            #pragma unroll
            for (int j = 0; j < 4; ++j) {
                float key = fmaf(-2.0f, acc[i][j][r], y2k[j]);   // > 0 always
                ull p = ((ull)__float_as_uint(key) << 32) | mj[j];
                mn = umin64(mn, p);
            }
            red2[rowl][wc * 16 + ra] = mn;
        }
    }
    __syncthreads();
    if (tid < 128) {
        const int l = tid & 63;
        ull mn = ~0ull;
        #pragma unroll
        for (int k = 0; k < 32; ++k)     // lane-staggered cols: distinct bank pairs
            mn = umin64(mn, red2[tid][(k + l) & 31]);
        atomicMin(&minpack[n0 + tid], mn);
    }
}

// ---------------------------------------------------------------------------
// Kernel 2: per-batch argmax of patch scores. Unpacks key -> d2 = key-1000+x2,
// pscore = sqrt(max(d2,0)); argmax over pscore (monotone in d2 per patch).
// ---------------------------------------------------------------------------
__global__ __launch_bounds__(256) void batch_argmax_kernel(
    const ull* __restrict__ minpack, const float* __restrict__ x2,
    float* __restrict__ pscore,
    float* __restrict__ bscore, int* __restrict__ bmaxp, int* __restrict__ bnn)
{
    __shared__ ull red[256];
    int b = blockIdx.x, tid = threadIdx.x;
    ull local = 0;
    for (int p = tid; p < P_PATCH; p += 256) {
        ull mp = minpack[b * P_PATCH + p];
        float key = __uint_as_float((unsigned)(mp >> 32));
        float d2 = key - 1000.0f + x2[b * P_PATCH + p];
        float sc = sqrtf(fmaxf(d2, 0.0f));
        pscore[b * P_PATCH + p] = sc;
        ull pk = ((ull)__float_as_uint(sc) << 32) | (unsigned)(p ^ 0xFFFFFFFFu);
        local = umax64(local, pk);
    }
    red[tid] = local;
    __syncthreads();
    for (int s = 128; s > 0; s >>= 1) {
        if (tid < s) red[tid] = umax64(red[tid], red[tid + s]);
        __syncthreads();
    }
    if (tid == 0) {
        ull r = red[0];
        int p = (int)(((unsigned)(r & 0xFFFFFFFFu)) ^ 0xFFFFFFFFu);
        bscore[b] = __uint_as_float((unsigned)(r >> 32));
        bmaxp[b]  = p;
        bnn[b]    = (int)(minpack[b * P_PATCH + p] & 0xFFFFFFFFu);
    }
}

// ---------------------------------------------------------------------------
// Kernel 3: d_nn = dist(nn_sample[b], memory_bank) -> (8, M)
// ---------------------------------------------------------------------------
__global__ __launch_bounds__(256) void dnn_kernel(
    const float* __restrict__ bank, const float* __restrict__ y2,
    const int* __restrict__ bnn, float* __restrict__ dnn)
{
    __shared__ float nn[BATCH][D_DIM];
    __shared__ float nny2[BATCH];
    int tid = threadIdx.x;
    for (int i = tid; i < BATCH * D_DIM; i += 256) {
        int b = i >> 7, d = i & 127;
        nn[b][d] = bank[(size_t)bnn[b] * D_DIM + d];
    }
    if (tid < BATCH) nny2[tid] = y2[bnn[tid]];
    __syncthreads();

    int w = tid >> 6, lane = tid & 63;
    int m = blockIdx.x * 4 + w;
    float2 v = *(const float2*)&bank[(size_t)m * D_DIM + 2 * lane];
    float part[BATCH];
    #pragma unroll
    for (int b = 0; b < BATCH; ++b)
        part[b] = fmaf(v.x, nn[b][2 * lane], v.y * nn[b][2 * lane + 1]);
    #pragma unroll
    for (int b = 0; b < BATCH; ++b) {
        float s = part[b];
        #pragma unroll
        for (int off = 32; off > 0; off >>= 1) s += __shfl_down(s, off, 64);
        if (lane == 0) {
            float d2 = nny2[b] + y2[m] - 2.0f * s;
            dnn[b * M_BANK + m] = sqrtf(fmaxf(d2, 0.0f));
        }
    }
}

// ---------------------------------------------------------------------------
// Kernel 4a: per-(batch, 1024-chunk) local top-9 of d_nn.
// ---------------------------------------------------------------------------
__global__ __launch_bounds__(256) void topk_part_kernel(
    const float* __restrict__ dnn, ull* __restrict__ cand)
{
    __shared__ ull vals[1024];
    __shared__ ull red[256];
    const int tid = threadIdx.x;
    const int b = blockIdx.y, ch = blockIdx.x;
    const int base = ch * 1024;

    #pragma unroll
    for (int j = 0; j < 4; ++j) {
        int i = base + tid + j * 256;
        vals[tid + j * 256] = ((ull)__float_as_uint(dnn[b * M_BANK + i]) << 32) | (unsigned)i;
    }
    __syncthreads();

    for (int k = 0; k < KNN; ++k) {
        ull local = vals[tid];
        #pragma unroll
        for (int j = 1; j < 4; ++j) local = umin64(local, vals[tid + j * 256]);
        red[tid] = local;
        __syncthreads();
        for (int s = 128; s > 0; s >>= 1) {
            if (tid < s) red[tid] = umin64(red[tid], red[tid + s]);
            __syncthreads();
        }
        ull win = red[0];
        if (tid == 0) cand[(b * 32 + ch) * KNN + k] = win;
        #pragma unroll
        for (int j = 0; j < 4; ++j)
            if (vals[tid + j * 256] == win) vals[tid + j * 256] = ~0ull;
        __syncthreads();
    }
}

// ---------------------------------------------------------------------------
// Kernel 4b: per-batch final top-9 from 288 candidates + rescore
// ---------------------------------------------------------------------------
__global__ __launch_bounds__(256) void topk_final_kernel(
    const ull* __restrict__ cand,
    const float* __restrict__ emb, const float* __restrict__ bank,
    const float* __restrict__ x2, const float* __restrict__ y2,
    const float* __restrict__ bscore, const int* __restrict__ bmaxp,
    float* __restrict__ out)
{
    __shared__ ull vals[512];
    __shared__ ull red[256];
    __shared__ int chosen[KNN];
    __shared__ float dists[KNN];
    const int tid = threadIdx.x;
    const int b = blockIdx.x;

    vals[tid]       = (tid < 32 * KNN) ? cand[b * 32 * KNN + tid] : ~0ull;
    vals[tid + 256] = (tid + 256 < 32 * KNN) ? cand[b * 32 * KNN + tid + 256] : ~0ull;
    __syncthreads();

    for (int k = 0; k < KNN; ++k) {
        red[tid] = umin64(vals[tid], vals[tid + 256]);
        __syncthreads();
        for (int s = 128; s > 0; s >>= 1) {
            if (tid < s) red[tid] = umin64(red[tid], red[tid + s]);
            __syncthreads();
        }
        ull win = red[0];
        if (tid == 0) chosen[k] = (int)(win & 0xFFFFFFFFu);
        if (vals[tid] == win) vals[tid] = ~0ull;
        if (vals[tid + 256] == win) vals[tid + 256] = ~0ull;
        __syncthreads();
    }

    const int e = b * P_PATCH + bmaxp[b];
    if (tid < KNN) {
        const float* mf = emb + (size_t)e * D_DIM;
        const float* ms = bank + (size_t)chosen[tid] * D_DIM;
        float dot = 0.0f;
        for (int d = 0; d < D_DIM; ++d) dot = fmaf(mf[d], ms[d], dot);
        float d2 = x2[e] - 2.0f * dot + y2[chosen[tid]];
        dists[tid] = sqrtf(fmaxf(d2, 0.0f));
    }
    __syncthreads();
    if (tid == 0) {
        float mx = dists[0];
        for (int k = 1; k < KNN; ++k) mx = fmaxf(mx, dists[k]);
        float s = 0.0f;
        for (int k = 0; k < KNN; ++k) s += expf(dists[k] - mx);
        float w = 1.0f - expf(dists[0] - mx) / s;
        out[b] = w * bscore[b];
    }
}

// ---------------------------------------------------------------------------
// Kernel 5: fully-fused resize + separable Gaussian blur (exact regroup).
// ---------------------------------------------------------------------------
__device__ __forceinline__ int refl224(int i) {
    if (i < 0) i = -i;
    if (i >= OUT_WH) i = 2 * (OUT_WH - 1) - i;
    return i;
}

__global__ __launch_bounds__(256) void blur_fused_kernel(
    const float* __restrict__ pscore, float* __restrict__ outp)
{
    __shared__ float g[KSIZE];
    __shared__ float ps[P_PATCH];
    __shared__ float q[GRID_WH * OUT_WH];
    __shared__ float hq[GRID_WH * OUT_WH];
    __shared__ float wrow[32][GRID_WH];

    const int tid = threadIdx.x;
    const int band = blockIdx.x;      // 0..6
    const int b    = blockIdx.y;      // 0..7

    if (tid < KSIZE) {
        float x = (tid - KRAD) * 0.25f;
        g[tid] = __expf(-0.5f * x * x);
    }
    for (int i = tid; i < P_PATCH; i += 256) ps[i] = pscore[b * P_PATCH + i];
    __syncthreads();
    if (tid == 0) {
        float s = 0.0f;
        for (int i = 0; i < KSIZE; ++i) s += g[i];
        float inv = 1.0f / s;
        for (int i = 0; i < KSIZE; ++i) g[i] *= inv;
    }
    __syncthreads();

    for (int i = tid; i < GRID_WH * OUT_WH; i += 256) {
        int gy = i / OUT_WH, x = i - gy * OUT_WH;
        float cx = (2 * x - 7) * 0.0625f;
        int ix = (int)floorf(cx); float fx = cx - ix;
        int x0 = min(max(ix, 0), GRID_WH - 1), x1 = min(max(ix + 1, 0), GRID_WH - 1);
        q[i] = ps[gy * GRID_WH + x0] * (1.0f - fx) + ps[gy * GRID_WH + x1] * fx;
    }

    if (tid < 32) {
        int y = band * 32 + tid;
        for (int gy = 0; gy < GRID_WH; ++gy) wrow[tid][gy] = 0.0f;
        for (int t = 0; t < KSIZE; ++t) {
            int yy = refl224(y - KRAD + t);
            float cy = (2 * yy - 7) * 0.0625f;
            int iy = (int)floorf(cy); float fy = cy - iy;
            int y0 = min(max(iy, 0), GRID_WH - 1), y1 = min(max(iy + 1, 0), GRID_WH - 1);
            wrow[tid][y0] += g[t] * (1.0f - fy);
            wrow[tid][y1] += g[t] * fy;
        }
    }
    __syncthreads();

    for (int i = tid; i < GRID_WH * OUT_WH; i += 256) {
        int gy = i / OUT_WH, x = i - gy * OUT_WH;
        float s = 0.0f;
        #pragma unroll
        for (int t = 0; t < KSIZE; ++t)
            s = fmaf(g[t], q[gy * OUT_WH + refl224(x - KRAD + t)], s);
        hq[i] = s;
    }
    __syncthreads();

    const int yl = tid >> 3;                 // 0..31
    const int xbase = (tid & 7) * 28;        // 8 groups x 28 px = 224
    const int y = band * 32 + yl;
    float* orow = outp + ((size_t)b * OUT_WH + y) * OUT_WH;
    for (int i = 0; i < 28; ++i) {
        int x = xbase + i;
        float s = 0.0f;
        #pragma unroll
        for (int gy = 0; gy < GRID_WH; ++gy)
            s = fmaf(wrow[yl][gy], hq[gy * OUT_WH + x], s);
        orow[x] = s;
    }
}

// ---------------------------------------------------------------------------
extern "C" void kernel_launch(void* const* d_in, const int* in_sizes, int n_in,
                              void* d_out, int out_size, void* d_ws, size_t ws_size,
                              hipStream_t stream) {
    const float* emb  = (const float*)d_in[0];
    const float* bank = (const float*)d_in[1];
    float* out = (float*)d_out;

    char* ws = (char*)d_ws;
    ull*   minpack = (ull*)(ws + WS_MINPACK);
    float* x2      = (float*)(ws + WS_X2);
    float* y2      = (float*)(ws + WS_Y2);
    float* pscore  = (float*)(ws + WS_PSCORE);
    float* bscore  = (float*)(ws + WS_BSCORE);
    int*   bmaxp   = (int*)(ws + WS_BMAXP);
    int*   bnn     = (int*)(ws + WS_BNN);
    float* dnn     = (float*)(ws + WS_DNN);
    unsigned short* Apk = (unsigned short*)(ws + WS_APK);
    unsigned short* Bpk = (unsigned short*)(ws + WS_BPK);
    ull*   cand    = (ull*)(ws + WS_CAND);

    // 0: split-pack + sumsq + minpack init (one wave per row)
    prep_kernel<<<(N_EMB + M_BANK) / 4, 256, 0, stream>>>(emb, bank, Apk, Bpk, x2, y2, minpack);
    // 1: MFMA distance + fused min/argmin (2-D grid; 128x128 tile, K=256 shared-B)
    {
        dim3 grid(M_BANK / 128, N_EMB / 128);   // 256 x 49
        mfma_min_kernel<<<grid, 256, 0, stream>>>(Apk, Bpk, y2, minpack);
    }
    // 2: per-batch argmax (+ pscore unpack: d2 = key-1000+x2)
    batch_argmax_kernel<<<BATCH, 256, 0, stream>>>(minpack, x2, pscore, bscore, bmaxp, bnn);
    // 3: d_nn
    dnn_kernel<<<M_BANK / 4, 256, 0, stream>>>(bank, y2, bnn, dnn);
    // 4a: per-chunk top-9 candidates
    {
        dim3 grid(32, BATCH);
        topk_part_kernel<<<grid, 256, 0, stream>>>(dnn, cand);
    }
    // 4b: final top-9 + rescore -> out[0..7]
    topk_final_kernel<<<BATCH, 256, 0, stream>>>(cand, emb, bank, x2, y2, bscore, bmaxp, out);
    // 5: fused resize + full separable blur -> out[8..]
    {
        dim3 grid(OUT_WH / 32, BATCH);
        blur_fused_kernel<<<grid, 256, 0, stream>>>(pscore, out + BATCH);
    }
}

// Round 8
// 267.303 us; speedup vs baseline: 1.5359x; 1.0353x over previous
//
#include <hip/hip_runtime.h>
#include <hip/hip_bf16.h>

// Problem constants (from setup_inputs)
#define N_EMB   6272
#define M_BANK  32768
#define D_DIM   128
#define KPA     256      // A packed: [hi(128) | lo(128)]
#define KPB     128      // B packed: [hi(128)]
#define BATCH   8
#define P_PATCH 784      // 6272 / 8
#define GRID_WH 28
#define OUT_WH  224
#define KNN     9
#define KSIZE   33
#define KRAD    16

typedef unsigned long long ull;
typedef short bf16x8 __attribute__((ext_vector_type(8)));
typedef float f32x4  __attribute__((ext_vector_type(4)));

// ---------------- workspace layout (bytes), ws ~256 MB ----------------
#define WS_MINPACK 0          // u64[6272]            -> 50176
#define WS_X2      50176      // f32[6272]            -> 75264
#define WS_Y2      75264      // f32[32768]           -> 206336
#define WS_PSCORE  206336     // f32[6272]            -> 231424
#define WS_BSCORE  231424     // f32[8]
#define WS_BMAXP   231456     // i32[8]
#define WS_BNN     231488     // i32[8]
#define WS_DNN     231552     // f32[8*32768]         -> 1280128
#define WS_APK     2885888    // u16[6272*256]        -> 6097408   (16B aligned)
#define WS_BPK     7702784    // u16[32768*128]       -> 16091392  (16B aligned)
#define WS_CAND    32868608   // u64[8*32*9]          -> 32887040

__device__ __forceinline__ ull umin64(ull a, ull b) { return a < b ? a : b; }
__device__ __forceinline__ ull umax64(ull a, ull b) { return a > b ? a : b; }

__device__ __forceinline__ void gload_lds16(const void* g, void* l) {
    __builtin_amdgcn_global_load_lds(
        (const __attribute__((address_space(1))) void*)g,
        (__attribute__((address_space(3))) void*)l, 16, 0, 0);
}

// ---------------------------------------------------------------------------
// Kernel 0 (prep): per-row bf16 hi/lo split-pack + sum-of-squares + minpack init.
// One wave per row. A rows: [hi|lo] (K=256); B rows: [hi] (K=128).
// ---------------------------------------------------------------------------
__global__ __launch_bounds__(256) void prep_kernel(
    const float* __restrict__ emb, const float* __restrict__ bank,
    unsigned short* __restrict__ Apk, unsigned short* __restrict__ Bpk,
    float* __restrict__ x2, float* __restrict__ y2, ull* __restrict__ minpack)
{
    const int tid = threadIdx.x;
    int gi = blockIdx.x * 256 + tid;
    if (gi < N_EMB) minpack[gi] = ~0ull;

    const int w    = blockIdx.x * 4 + (tid >> 6);
    const int lane = tid & 63;

    float2 v;
    float s;
    if (w < N_EMB) {
        const float* src = emb + (size_t)w * D_DIM;
        v = *(const float2*)&src[2 * lane];
        __hip_bfloat16 h0 = __float2bfloat16(v.x);
        __hip_bfloat16 h1 = __float2bfloat16(v.y);
        __hip_bfloat16 l0 = __float2bfloat16(v.x - __bfloat162float(h0));
        __hip_bfloat16 l1 = __float2bfloat16(v.y - __bfloat162float(h1));
        unsigned hb0 = *(unsigned short*)&h0, hb1 = *(unsigned short*)&h1;
        unsigned lb0 = *(unsigned short*)&l0, lb1 = *(unsigned short*)&l1;
        unsigned short* dst = Apk + (size_t)w * KPA;
        *(unsigned*)&dst[2 * lane]       = hb0 | (hb1 << 16);
        *(unsigned*)&dst[128 + 2 * lane] = lb0 | (lb1 << 16);
        s = fmaf(v.x, v.x, v.y * v.y);
        #pragma unroll
        for (int off = 32; off > 0; off >>= 1) s += __shfl_down(s, off, 64);
        if (lane == 0) x2[w] = s;
    } else {
        int m = w - N_EMB;             // grid sized exactly -> m < M_BANK
        const float* src = bank + (size_t)m * D_DIM;
        v = *(const float2*)&src[2 * lane];
        __hip_bfloat16 h0 = __float2bfloat16(v.x);
        __hip_bfloat16 h1 = __float2bfloat16(v.y);
        unsigned hb0 = *(unsigned short*)&h0, hb1 = *(unsigned short*)&h1;
        unsigned short* dst = Bpk + (size_t)m * KPB;
        *(unsigned*)&dst[2 * lane] = hb0 | (hb1 << 16);
        s = fmaf(v.x, v.x, v.y * v.y);
        #pragma unroll
        for (int off = 32; off > 0; off >>= 1) s += __shfl_down(s, off, 64);
        if (lane == 0) y2[m] = s;
    }
}

// ---------------------------------------------------------------------------
// Kernel 1: MFMA distance + fused min/argmin.
// 128x128 tile, K=256 shared-B, 8 half-steps (32 KB LDS, A/B dbuf panels).
// R8 = R6's proven dataflow (bfr held in VGPRs across each hi/lo step pair;
// B read from LDS only on even steps) + a scheduling-only fix for R6's
// scratch spill: each step's A-fragment consumption is split into two
// halves with __builtin_amdgcn_sched_barrier(0) between them, so at most
// 2 af fragments (8 VGPRs) are live on top of bfr (16) -> peak ~61 arch
// VGPR <= 64 -> no spill at __launch_bounds__(256,4). MFMA order unchanged
// (i-major, j-minor) -> bit-identical numerics to R6.
// Epilogue: key = y2[m]+1000 - 2*dot (row-constant x2 dropped; argmin-
// equivalent per row; +1000 keeps keys positive -> float-bit u64 monotone).
// ---------------------------------------------------------------------------
__global__ __launch_bounds__(256, 4) void mfma_min_kernel(
    const unsigned short* __restrict__ Apk, const unsigned short* __restrict__ Bpk,
    const float* __restrict__ y2, ull* __restrict__ minpack)
{
    __shared__ __align__(16) unsigned short smem[4 * 128 * 32];  // 32 KB
    const int PAN = 128 * 32;   // 4096 elems = 8 KB panel
    // panels: A0=smem[0], A1=smem[PAN], B0=smem[2*PAN], B1=smem[3*PAN]

    const int tid  = threadIdx.x;
    const int lane = tid & 63;
    const int wave = tid >> 6;
    const int wr = wave >> 1, wc = wave & 1;
    const int n0 = blockIdx.y * 128;
    const int m0 = blockIdx.x * 128;

    const int srow = tid >> 2;   // 0..63 staging base row
    const int sseg = tid & 3;    // 16B segment (LDS phys)
    const int ssw  = sseg ^ ((srow >> 1) & 3);   // swizzled GLOBAL segment

    const int qa = lane >> 4;    // k-quad (logical)
    const int ra = lane & 15;    // row-in-frag / col-in-C
    const int qsw = qa ^ ((ra >> 1) & 3);        // swizzled LDS segment to read

    f32x4 acc[4][4];
    #pragma unroll
    for (int i = 0; i < 4; ++i)
        #pragma unroll
        for (int j = 0; j < 4; ++j)
            acc[i][j] = (f32x4){0.f, 0.f, 0.f, 0.f};

    const unsigned short* gA = Apk + (size_t)(n0 + srow) * KPA + ssw * 8;
    const unsigned short* gB = Bpk + (size_t)(m0 + srow) * KPB + ssw * 8;
    const int lof0 = srow * 32 + sseg * 8;            // linear LDS dests
    const int lof1 = (srow + 64) * 32 + sseg * 8;

    // A panel column base for step s: hi/lo interleave.
    #define ACOL(s) ((((s) & 1) * 128) + (((s) >> 1) * 32))

    // prologue: A panel 0 -> A0, B(0) -> B0
    gload_lds16(gA,            &smem[lof0]);
    gload_lds16(gA + 64 * KPA, &smem[lof1]);
    gload_lds16(gB,            &smem[2 * PAN + lof0]);
    gload_lds16(gB + 64 * KPB, &smem[2 * PAN + lof1]);

    bf16x8 bfr[4];   // B fragments, held across the hi/lo step pair

    #define STEP(s, VM) { \
        /* barrier#1: all waves done reading the buffers we now overwrite */ \
        asm volatile("s_barrier" ::: "memory"); \
        if ((s) < 7) { \
            const int ab = ((s) + 1) & 1; \
            gload_lds16(gA + ACOL((s) + 1),            &smem[ab * PAN + lof0]); \
            gload_lds16(gA + ACOL((s) + 1) + 64 * KPA, &smem[ab * PAN + lof1]); \
        } \
        if (((s) & 1) == 0 && (s) < 6) { \
            const int cn = ((s) >> 1) + 1; \
            const int bb = cn & 1; \
            gload_lds16(gB + cn * 32,            &smem[(2 + bb) * PAN + lof0]); \
            gload_lds16(gB + cn * 32 + 64 * KPB, &smem[(2 + bb) * PAN + lof1]); \
        } \
        /* wait: previous step's loads complete; this step's stay in flight */ \
        asm volatile("s_waitcnt vmcnt(" #VM ")" ::: "memory"); \
        /* barrier#2: current panels complete in every wave */ \
        asm volatile("s_barrier" ::: "memory"); \
        const unsigned short* As = &smem[((s) & 1) * PAN]; \
        if (((s) & 1) == 0) { \
            const unsigned short* Bs = &smem[(2 + (((s) >> 1) & 1)) * PAN]; \
            _Pragma("unroll") \
            for (int j = 0; j < 4; ++j) \
                bfr[j] = *(const bf16x8*)&Bs[(wc * 64 + j * 16 + ra) * 32 + qsw * 8]; \
        } \
        { \
            bf16x8 af0 = *(const bf16x8*)&As[(wr * 64 +  0 + ra) * 32 + qsw * 8]; \
            bf16x8 af1 = *(const bf16x8*)&As[(wr * 64 + 16 + ra) * 32 + qsw * 8]; \
            _Pragma("unroll") \
            for (int j = 0; j < 4; ++j) \
                acc[0][j] = __builtin_amdgcn_mfma_f32_16x16x32_bf16(af0, bfr[j], acc[0][j], 0, 0, 0); \
            _Pragma("unroll") \
            for (int j = 0; j < 4; ++j) \
                acc[1][j] = __builtin_amdgcn_mfma_f32_16x16x32_bf16(af1, bfr[j], acc[1][j], 0, 0, 0); \
            __builtin_amdgcn_sched_barrier(0); \
            bf16x8 af2 = *(const bf16x8*)&As[(wr * 64 + 32 + ra) * 32 + qsw * 8]; \
            bf16x8 af3 = *(const bf16x8*)&As[(wr * 64 + 48 + ra) * 32 + qsw * 8]; \
            _Pragma("unroll") \
            for (int j = 0; j < 4; ++j) \
                acc[2][j] = __builtin_amdgcn_mfma_f32_16x16x32_bf16(af2, bfr[j], acc[2][j], 0, 0, 0); \
            _Pragma("unroll") \
            for (int j = 0; j < 4; ++j) \
                acc[3][j] = __builtin_amdgcn_mfma_f32_16x16x32_bf16(af3, bfr[j], acc[3][j], 0, 0, 0); \
        } \
    }

    STEP(0, 4) STEP(1, 2) STEP(2, 4) STEP(3, 2)
    STEP(4, 4) STEP(5, 2) STEP(6, 2) STEP(7, 0)
    #undef STEP
    #undef ACOL

    // ---- epilogue: key = y2[m]+1000 - 2*dot; pack; LDS transpose-reduce ----
    float y2k[4];
    unsigned mj[4];
    #pragma unroll
    for (int j = 0; j < 4; ++j) {
        const int m = m0 + wc * 64 + j * 16 + ra;
        y2k[j] = y2[m] + 1000.0f;
        mj[j]  = (unsigned)m;
    }

    ull (*red2)[32] = (ull (*)[32])smem;   // 128 rows x 32 = 32 KB (whole smem)

    // all waves must be done reading the K-panels before red2 overwrites them
    __syncthreads();

    #pragma unroll
    for (int i = 0; i < 4; ++i) {
        #pragma unroll
        for (int r = 0; r < 4; ++r) {
            const int rowl = wr * 64 + i * 16 + qa * 4 + r;
            ull mn = ~0ull;
            #pragma unroll
            for (int j = 0; j < 4; ++j) {
                float key = fmaf(-2.0f, acc[i][j][r], y2k[j]);   // > 0 always
                ull p = ((ull)__float_as_uint(key) << 32) | mj[j];
                mn = umin64(mn, p);
            }
            red2[rowl][wc * 16 + ra] = mn;
        }
    }
    __syncthreads();
    if (tid < 128) {
        const int l = tid & 63;
        ull mn = ~0ull;
        #pragma unroll
        for (int k = 0; k < 32; ++k)     // lane-staggered cols: distinct bank pairs
            mn = umin64(mn, red2[tid][(k + l) & 31]);
        atomicMin(&minpack[n0 + tid], mn);
    }
}

// ---------------------------------------------------------------------------
// Kernel 2: per-batch argmax of patch scores. Unpacks key -> d2 = key-1000+x2,
// pscore = sqrt(max(d2,0)); argmax over pscore (monotone in d2 per patch).
// ---------------------------------------------------------------------------
__global__ __launch_bounds__(256) void batch_argmax_kernel(
    const ull* __restrict__ minpack, const float* __restrict__ x2,
    float* __restrict__ pscore,
    float* __restrict__ bscore, int* __restrict__ bmaxp, int* __restrict__ bnn)
{
    __shared__ ull red[256];
    int b = blockIdx.x, tid = threadIdx.x;
    ull local = 0;
    for (int p = tid; p < P_PATCH; p += 256) {
        ull mp = minpack[b * P_PATCH + p];
        float key = __uint_as_float((unsigned)(mp >> 32));
        float d2 = key - 1000.0f + x2[b * P_PATCH + p];
        float sc = sqrtf(fmaxf(d2, 0.0f));
        pscore[b * P_PATCH + p] = sc;
        ull pk = ((ull)__float_as_uint(sc) << 32) | (unsigned)(p ^ 0xFFFFFFFFu);
        local = umax64(local, pk);
    }
    red[tid] = local;
    __syncthreads();
    for (int s = 128; s > 0; s >>= 1) {
        if (tid < s) red[tid] = umax64(red[tid], red[tid + s]);
        __syncthreads();
    }
    if (tid == 0) {
        ull r = red[0];
        int p = (int)(((unsigned)(r & 0xFFFFFFFFu)) ^ 0xFFFFFFFFu);
        bscore[b] = __uint_as_float((unsigned)(r >> 32));
        bmaxp[b]  = p;
        bnn[b]    = (int)(minpack[b * P_PATCH + p] & 0xFFFFFFFFu);
    }
}

// ---------------------------------------------------------------------------
// Kernel 3: d_nn = dist(nn_sample[b], memory_bank) -> (8, M)
// ---------------------------------------------------------------------------
__global__ __launch_bounds__(256) void dnn_kernel(
    const float* __restrict__ bank, const float* __restrict__ y2,
    const int* __restrict__ bnn, float* __restrict__ dnn)
{
    __shared__ float nn[BATCH][D_DIM];
    __shared__ float nny2[BATCH];
    int tid = threadIdx.x;
    for (int i = tid; i < BATCH * D_DIM; i += 256) {
        int b = i >> 7, d = i & 127;
        nn[b][d] = bank[(size_t)bnn[b] * D_DIM + d];
    }
    if (tid < BATCH) nny2[tid] = y2[bnn[tid]];
    __syncthreads();

    int w = tid >> 6, lane = tid & 63;
    int m = blockIdx.x * 4 + w;
    float2 v = *(const float2*)&bank[(size_t)m * D_DIM + 2 * lane];
    float part[BATCH];
    #pragma unroll
    for (int b = 0; b < BATCH; ++b)
        part[b] = fmaf(v.x, nn[b][2 * lane], v.y * nn[b][2 * lane + 1]);
    #pragma unroll
    for (int b = 0; b < BATCH; ++b) {
        float s = part[b];
        #pragma unroll
        for (int off = 32; off > 0; off >>= 1) s += __shfl_down(s, off, 64);
        if (lane == 0) {
            float d2 = nny2[b] + y2[m] - 2.0f * s;
            dnn[b * M_BANK + m] = sqrtf(fmaxf(d2, 0.0f));
        }
    }
}

// ---------------------------------------------------------------------------
// Kernel 4a: per-(batch, 1024-chunk) local top-9 of d_nn.
// ---------------------------------------------------------------------------
__global__ __launch_bounds__(256) void topk_part_kernel(
    const float* __restrict__ dnn, ull* __restrict__ cand)
{
    __shared__ ull vals[1024];
    __shared__ ull red[256];
    const int tid = threadIdx.x;
    const int b = blockIdx.y, ch = blockIdx.x;
    const int base = ch * 1024;

    #pragma unroll
    for (int j = 0; j < 4; ++j) {
        int i = base + tid + j * 256;
        vals[tid + j * 256] = ((ull)__float_as_uint(dnn[b * M_BANK + i]) << 32) | (unsigned)i;
    }
    __syncthreads();

    for (int k = 0; k < KNN; ++k) {
        ull local = vals[tid];
        #pragma unroll
        for (int j = 1; j < 4; ++j) local = umin64(local, vals[tid + j * 256]);
        red[tid] = local;
        __syncthreads();
        for (int s = 128; s > 0; s >>= 1) {
            if (tid < s) red[tid] = umin64(red[tid], red[tid + s]);
            __syncthreads();
        }
        ull win = red[0];
        if (tid == 0) cand[(b * 32 + ch) * KNN + k] = win;
        #pragma unroll
        for (int j = 0; j < 4; ++j)
            if (vals[tid + j * 256] == win) vals[tid + j * 256] = ~0ull;
        __syncthreads();
    }
}

// ---------------------------------------------------------------------------
// Kernel 4b: per-batch final top-9 from 288 candidates + rescore
// ---------------------------------------------------------------------------
__global__ __launch_bounds__(256) void topk_final_kernel(
    const ull* __restrict__ cand,
    const float* __restrict__ emb, const float* __restrict__ bank,
    const float* __restrict__ x2, const float* __restrict__ y2,
    const float* __restrict__ bscore, const int* __restrict__ bmaxp,
    float* __restrict__ out)
{
    __shared__ ull vals[512];
    __shared__ ull red[256];
    __shared__ int chosen[KNN];
    __shared__ float dists[KNN];
    const int tid = threadIdx.x;
    const int b = blockIdx.x;

    vals[tid]       = (tid < 32 * KNN) ? cand[b * 32 * KNN + tid] : ~0ull;
    vals[tid + 256] = (tid + 256 < 32 * KNN) ? cand[b * 32 * KNN + tid + 256] : ~0ull;
    __syncthreads();

    for (int k = 0; k < KNN; ++k) {
        red[tid] = umin64(vals[tid], vals[tid + 256]);
        __syncthreads();
        for (int s = 128; s > 0; s >>= 1) {
            if (tid < s) red[tid] = umin64(red[tid], red[tid + s]);
            __syncthreads();
        }
        ull win = red[0];
        if (tid == 0) chosen[k] = (int)(win & 0xFFFFFFFFu);
        if (vals[tid] == win) vals[tid] = ~0ull;
        if (vals[tid + 256] == win) vals[tid + 256] = ~0ull;
        __syncthreads();
    }

    const int e = b * P_PATCH + bmaxp[b];
    if (tid < KNN) {
        const float* mf = emb + (size_t)e * D_DIM;
        const float* ms = bank + (size_t)chosen[tid] * D_DIM;
        float dot = 0.0f;
        for (int d = 0; d < D_DIM; ++d) dot = fmaf(mf[d], ms[d], dot);
        float d2 = x2[e] - 2.0f * dot + y2[chosen[tid]];
        dists[tid] = sqrtf(fmaxf(d2, 0.0f));
    }
    __syncthreads();
    if (tid == 0) {
        float mx = dists[0];
        for (int k = 1; k < KNN; ++k) mx = fmaxf(mx, dists[k]);
        float s = 0.0f;
        for (int k = 0; k < KNN; ++k) s += expf(dists[k] - mx);
        float w = 1.0f - expf(dists[0] - mx) / s;
        out[b] = w * bscore[b];
    }
}

// ---------------------------------------------------------------------------
// Kernel 5: fully-fused resize + separable Gaussian blur (exact regroup).
// ---------------------------------------------------------------------------
__device__ __forceinline__ int refl224(int i) {
    if (i < 0) i = -i;
    if (i >= OUT_WH) i = 2 * (OUT_WH - 1) - i;
    return i;
}

__global__ __launch_bounds__(256) void blur_fused_kernel(
    const float* __restrict__ pscore, float* __restrict__ outp)
{
    __shared__ float g[KSIZE];
    __shared__ float ps[P_PATCH];
    __shared__ float q[GRID_WH * OUT_WH];
    __shared__ float hq[GRID_WH * OUT_WH];
    __shared__ float wrow[32][GRID_WH];

    const int tid = threadIdx.x;
    const int band = blockIdx.x;      // 0..6
    const int b    = blockIdx.y;      // 0..7

    if (tid < KSIZE) {
        float x = (tid - KRAD) * 0.25f;
        g[tid] = __expf(-0.5f * x * x);
    }
    for (int i = tid; i < P_PATCH; i += 256) ps[i] = pscore[b * P_PATCH + i];
    __syncthreads();
    if (tid == 0) {
        float s = 0.0f;
        for (int i = 0; i < KSIZE; ++i) s += g[i];
        float inv = 1.0f / s;
        for (int i = 0; i < KSIZE; ++i) g[i] *= inv;
    }
    __syncthreads();

    for (int i = tid; i < GRID_WH * OUT_WH; i += 256) {
        int gy = i / OUT_WH, x = i - gy * OUT_WH;
        float cx = (2 * x - 7) * 0.0625f;
        int ix = (int)floorf(cx); float fx = cx - ix;
        int x0 = min(max(ix, 0), GRID_WH - 1), x1 = min(max(ix + 1, 0), GRID_WH - 1);
        q[i] = ps[gy * GRID_WH + x0] * (1.0f - fx) + ps[gy * GRID_WH + x1] * fx;
    }

    if (tid < 32) {
        int y = band * 32 + tid;
        for (int gy = 0; gy < GRID_WH; ++gy) wrow[tid][gy] = 0.0f;
        for (int t = 0; t < KSIZE; ++t) {
            int yy = refl224(y - KRAD + t);
            float cy = (2 * yy - 7) * 0.0625f;
            int iy = (int)floorf(cy); float fy = cy - iy;
            int y0 = min(max(iy, 0), GRID_WH - 1), y1 = min(max(iy + 1, 0), GRID_WH - 1);
            wrow[tid][y0] += g[t] * (1.0f - fy);
            wrow[tid][y1] += g[t] * fy;
        }
    }
    __syncthreads();

    for (int i = tid; i < GRID_WH * OUT_WH; i += 256) {
        int gy = i / OUT_WH, x = i - gy * OUT_WH;
        float s = 0.0f;
        #pragma unroll
        for (int t = 0; t < KSIZE; ++t)
            s = fmaf(g[t], q[gy * OUT_WH + refl224(x - KRAD + t)], s);
        hq[i] = s;
    }
    __syncthreads();

    const int yl = tid >> 3;                 // 0..31
    const int xbase = (tid & 7) * 28;        // 8 groups x 28 px = 224
    const int y = band * 32 + yl;
    float* orow = outp + ((size_t)b * OUT_WH + y) * OUT_WH;
    for (int i = 0; i < 28; ++i) {
        int x = xbase + i;
        float s = 0.0f;
        #pragma unroll
        for (int gy = 0; gy < GRID_WH; ++gy)
            s = fmaf(wrow[yl][gy], hq[gy * OUT_WH + x], s);
        orow[x] = s;
    }
}

// ---------------------------------------------------------------------------
extern "C" void kernel_launch(void* const* d_in, const int* in_sizes, int n_in,
                              void* d_out, int out_size, void* d_ws, size_t ws_size,
                              hipStream_t stream) {
    const float* emb  = (const float*)d_in[0];
    const float* bank = (const float*)d_in[1];
    float* out = (float*)d_out;

    char* ws = (char*)d_ws;
    ull*   minpack = (ull*)(ws + WS_MINPACK);
    float* x2      = (float*)(ws + WS_X2);
    float* y2      = (float*)(ws + WS_Y2);
    float* pscore  = (float*)(ws + WS_PSCORE);
    float* bscore  = (float*)(ws + WS_BSCORE);
    int*   bmaxp   = (int*)(ws + WS_BMAXP);
    int*   bnn     = (int*)(ws + WS_BNN);
    float* dnn     = (float*)(ws + WS_DNN);
    unsigned short* Apk = (unsigned short*)(ws + WS_APK);
    unsigned short* Bpk = (unsigned short*)(ws + WS_BPK);
    ull*   cand    = (ull*)(ws + WS_CAND);

    // 0: split-pack + sumsq + minpack init (one wave per row)
    prep_kernel<<<(N_EMB + M_BANK) / 4, 256, 0, stream>>>(emb, bank, Apk, Bpk, x2, y2, minpack);
    // 1: MFMA distance + fused min/argmin (2-D grid; 128x128 tile, K=256 shared-B)
    {
        dim3 grid(M_BANK / 128, N_EMB / 128);   // 256 x 49
        mfma_min_kernel<<<grid, 256, 0, stream>>>(Apk, Bpk, y2, minpack);
    }
    // 2: per-batch argmax (+ pscore unpack: d2 = key-1000+x2)
    batch_argmax_kernel<<<BATCH, 256, 0, stream>>>(minpack, x2, pscore, bscore, bmaxp, bnn);
    // 3: d_nn
    dnn_kernel<<<M_BANK / 4, 256, 0, stream>>>(bank, y2, bnn, dnn);
    // 4a: per-chunk top-9 candidates
    {
        dim3 grid(32, BATCH);
        topk_part_kernel<<<grid, 256, 0, stream>>>(dnn, cand);
    }
    // 4b: final top-9 + rescore -> out[0..7]
    topk_final_kernel<<<BATCH, 256, 0, stream>>>(cand, emb, bank, x2, y2, bscore, bmaxp, out);
    // 5: fused resize + full separable blur -> out[8..]
    {
        dim3 grid(OUT_WH / 32, BATCH);
        blur_fused_kernel<<<grid, 256, 0, stream>>>(pscore, out + BATCH);
    }
}